// Round 1
// baseline (873.865 us; speedup 1.0000x reference)
//
#include <hip/hip_runtime.h>
#include <hip/hip_bf16.h>
#include <cstdint>
#include <cstddef>

// GraphSAGE 2-layer: h1 = mean_agg(x@W1_l) + b1 + x@W1_r ; h2 = mean_agg(h1@W2_l) + b2 + h1@W2_r
// out = log_softmax(relu(h2))
//
// Pipeline:
//   k_gemm1  : x[50000,1433] @ [W1_l|W1_r] -> h1pre[50000,128] (cols 0..63 msg, 64..127 self)
//   k_hist/scan/fill : build dst-CSR (deg, off, esrc) each call (d_ws not re-poisoned but we rebuild)
//   k_agg1   : per-dst wave: mean over neighbors of msg + b1 + self -> h1[50000,64]
//   k_gemm2  : h1 @ [W2_l|W2_r] -> m2[50000,64] (cols 0..31 msg2, 32..63 self2)
//   k_agg2   : per-dst half-wave: mean + b2 + self2, relu, log_softmax(32) -> out

#define N_NODES 50000
#define N_EDGES 800000
#define F_IN    1433

// ---- workspace layout (bytes) ----
static constexpr size_t OFF_H1PRE = 0;                               // 50000*128*4 = 25,600,000
static constexpr size_t OFF_H1    = OFF_H1PRE + 25600000;            // 50000*64*4  = 12,800,000
static constexpr size_t OFF_M2    = OFF_H1    + 12800000;            // 50000*64*4  = 12,800,000
static constexpr size_t OFF_DEG   = OFF_M2    + 12800000;            // 50000*4
static constexpr size_t OFF_OFFS  = OFF_DEG   + 200000;              // 50000*4
static constexpr size_t OFF_CUR   = OFF_OFFS  + 200000;              // 50000*4
static constexpr size_t OFF_ESRC  = OFF_CUR   + 200000;              // 800000*4
static constexpr size_t OFF_BSUM  = OFF_ESRC  + 3200000;             // 25*4 (pad 256)
static constexpr size_t OFF_BOFF  = OFF_BSUM  + 256;                 // 25*4

// ---------------- GEMM1: 32-row x 128-col tiles, fp32 ----------------
__global__ __launch_bounds__(256) void k_gemm1(const float* __restrict__ x,
                                               const float* __restrict__ Wl,
                                               const float* __restrict__ Wr,
                                               float* __restrict__ outp) {
  __shared__ __align__(16) float As[16][36];   // [k][row], pad->stride 36 (2-way max, free)
  __shared__ __align__(16) float Bs[16][128];  // [k][col]
  const int t   = threadIdx.x;
  const int tc  = t & 31;   // col group: cols 4*tc..4*tc+3
  const int tr  = t >> 5;   // row group: rows 4*tr..4*tr+3
  const int row0 = blockIdx.x * 32;

  float acc[4][4] = {};

  for (int k0 = 0; k0 < F_IN; k0 += 16) {
    // stage A tile: 32 rows x 16 k
#pragma unroll
    for (int i = 0; i < 2; ++i) {
      int idx = t + 256 * i;          // 0..511
      int r = idx >> 4, k = idx & 15;
      int gr = row0 + r, gk = k0 + k;
      float v = 0.f;
      if (gr < N_NODES && gk < F_IN) v = x[(size_t)gr * F_IN + gk];
      As[k][r] = v;
    }
    // stage B tile: 16 k x 128 cols (cols 0..63 = W1_l, 64..127 = W1_r)
#pragma unroll
    for (int i = 0; i < 8; ++i) {
      int idx = t + 256 * i;          // 0..2047
      int k = idx >> 7, c = idx & 127;
      int gk = k0 + k;
      float v = 0.f;
      if (gk < F_IN) v = (c < 64) ? Wl[gk * 64 + c] : Wr[gk * 64 + (c - 64)];
      Bs[k][c] = v;
    }
    __syncthreads();
#pragma unroll
    for (int k = 0; k < 16; ++k) {
      const float4 a = *(const float4*)(&As[k][4 * tr]);
      const float4 b = *(const float4*)(&Bs[k][4 * tc]);
      const float av[4] = {a.x, a.y, a.z, a.w};
      const float bv[4] = {b.x, b.y, b.z, b.w};
#pragma unroll
      for (int r = 0; r < 4; ++r)
#pragma unroll
        for (int c = 0; c < 4; ++c)
          acc[r][c] = fmaf(av[r], bv[c], acc[r][c]);
    }
    __syncthreads();
  }

#pragma unroll
  for (int r = 0; r < 4; ++r) {
    int gr = row0 + 4 * tr + r;
    if (gr < N_NODES) {
      float4 o = make_float4(acc[r][0], acc[r][1], acc[r][2], acc[r][3]);
      *(float4*)(&outp[(size_t)gr * 128 + 4 * tc]) = o;
    }
  }
}

// ---------------- CSR build ----------------
__global__ void k_hist(const int* __restrict__ ei, int* __restrict__ deg) {
  int e = blockIdx.x * blockDim.x + threadIdx.x;
  if (e < N_EDGES) atomicAdd(&deg[ei[N_EDGES + e]], 1);
}

__global__ __launch_bounds__(256) void k_scan_a(const int* __restrict__ deg,
                                                int* __restrict__ off,
                                                int* __restrict__ blksum) {
  __shared__ int sd[256];
  const int t = threadIdx.x;
  const int base = blockIdx.x * 2048 + t * 8;
  int v[8];
  int s = 0;
#pragma unroll
  for (int j = 0; j < 8; ++j) {
    int i = base + j;
    v[j] = (i < N_NODES) ? deg[i] : 0;
    s += v[j];
  }
  sd[t] = s;
  __syncthreads();
  for (int o = 1; o < 256; o <<= 1) {
    int u = (t >= o) ? sd[t - o] : 0;
    __syncthreads();
    sd[t] += u;
    __syncthreads();
  }
  int excl = sd[t] - s;  // exclusive prefix of this thread's chunk (block-local)
#pragma unroll
  for (int j = 0; j < 8; ++j) {
    int i = base + j;
    if (i < N_NODES) off[i] = excl;
    excl += v[j];
  }
  if (t == 255) blksum[blockIdx.x] = sd[255];
}

__global__ void k_scan_b(const int* __restrict__ blksum, int* __restrict__ blkoff) {
  if (threadIdx.x == 0) {
    int run = 0;
    for (int i = 0; i < 25; ++i) { blkoff[i] = run; run += blksum[i]; }
  }
}

__global__ void k_scan_c(int* __restrict__ off, int* __restrict__ cur,
                         const int* __restrict__ blkoff) {
  int i = blockIdx.x * blockDim.x + threadIdx.x;
  if (i < N_NODES) {
    int v = off[i] + blkoff[i >> 11];
    off[i] = v;
    cur[i] = v;
  }
}

__global__ void k_fill(const int* __restrict__ ei, int* __restrict__ cur,
                       int* __restrict__ esrc) {
  int e = blockIdx.x * blockDim.x + threadIdx.x;
  if (e < N_EDGES) {
    int s = ei[e];
    int d = ei[N_EDGES + e];
    int slot = atomicAdd(&cur[d], 1);
    esrc[slot] = s;
  }
}

// ---------------- aggregate layer 1: one wave (64 lanes = 64 feats) per dst ----------------
__global__ __launch_bounds__(256) void k_agg1(const float* __restrict__ h1pre,
                                              const int* __restrict__ off,
                                              const int* __restrict__ deg,
                                              const int* __restrict__ esrc,
                                              const float* __restrict__ b1,
                                              float* __restrict__ h1) {
  const int lane = threadIdx.x & 63;
  const int d = blockIdx.x * 4 + (threadIdx.x >> 6);
  if (d >= N_NODES) return;
  const int dg = deg[d];
  const int base = off[d];
  float acc = 0.f;
  for (int j = 0; j < dg; ++j) {
    int s = esrc[base + j];
    acc += h1pre[(size_t)s * 128 + lane];
  }
  const float inv = (dg > 0) ? 1.f / (float)dg : 0.f;
  h1[(size_t)d * 64 + lane] = acc * inv + b1[lane] + h1pre[(size_t)d * 128 + 64 + lane];
}

// ---------------- GEMM2: h1[50000,64] @ [W2_l|W2_r][64,64] -> m2[50000,64] ----------------
__global__ __launch_bounds__(256) void k_gemm2(const float* __restrict__ h1,
                                               const float* __restrict__ W2l,
                                               const float* __restrict__ W2r,
                                               float* __restrict__ m2) {
  __shared__ __align__(16) float Ws[64][68];
  __shared__ __align__(16) float Hs[32][68];
  const int t = threadIdx.x;
#pragma unroll
  for (int i = 0; i < 16; ++i) {
    int idx = t + 256 * i;          // 0..4095
    int k = idx >> 6, c = idx & 63;
    Ws[k][c] = (c < 32) ? W2l[k * 32 + c] : W2r[k * 32 + (c - 32)];
  }
  const int r0 = blockIdx.x * 32;
#pragma unroll
  for (int i = 0; i < 8; ++i) {
    int idx = t + 256 * i;          // 0..2047
    int r = idx >> 6, c = idx & 63;
    int gr = r0 + r;
    Hs[r][c] = (gr < N_NODES) ? h1[(size_t)gr * 64 + c] : 0.f;
  }
  __syncthreads();
  const int rl = t >> 3;            // 0..31
  const int c0 = (t & 7) * 8;       // 0,8,..,56
  float acc[8] = {};
#pragma unroll 8
  for (int k = 0; k < 64; ++k) {
    float hv = Hs[rl][k];
#pragma unroll
    for (int j = 0; j < 8; ++j) acc[j] = fmaf(hv, Ws[k][c0 + j], acc[j]);
  }
  const int gr = r0 + rl;
  if (gr < N_NODES) {
    *(float4*)(&m2[(size_t)gr * 64 + c0])     = make_float4(acc[0], acc[1], acc[2], acc[3]);
    *(float4*)(&m2[(size_t)gr * 64 + c0 + 4]) = make_float4(acc[4], acc[5], acc[6], acc[7]);
  }
}

// ---------------- aggregate layer 2 + relu + log_softmax: half-wave (32 lanes) per dst ----------------
__global__ __launch_bounds__(256) void k_agg2(const float* __restrict__ m2,
                                              const int* __restrict__ off,
                                              const int* __restrict__ deg,
                                              const int* __restrict__ esrc,
                                              const float* __restrict__ b2,
                                              float* __restrict__ out) {
  const int lane = threadIdx.x & 63;
  const int half = lane >> 5;
  const int f = lane & 31;
  const int d = blockIdx.x * 8 + ((threadIdx.x >> 6) << 1) + half;  // 50000 % 8 == 0 -> no tail
  const int dg = deg[d];
  const int base = off[d];
  float acc = 0.f;
  for (int j = 0; j < dg; ++j) {
    int s = esrc[base + j];
    acc += m2[(size_t)s * 64 + f];
  }
  const float inv = (dg > 0) ? 1.f / (float)dg : 0.f;
  float v = acc * inv + b2[f] + m2[(size_t)d * 64 + 32 + f];
  v = fmaxf(v, 0.f);
  float m = v;
#pragma unroll
  for (int o = 16; o > 0; o >>= 1) m = fmaxf(m, __shfl_xor(m, o, 32));
  float e = expf(v - m);
  float sum = e;
#pragma unroll
  for (int o = 16; o > 0; o >>= 1) sum += __shfl_xor(sum, o, 32);
  out[(size_t)d * 32 + f] = v - m - logf(sum);
}

extern "C" void kernel_launch(void* const* d_in, const int* in_sizes, int n_in,
                              void* d_out, int out_size, void* d_ws, size_t ws_size,
                              hipStream_t stream) {
  const float* x   = (const float*)d_in[0];
  const int*   ei  = (const int*)d_in[1];
  const float* W1l = (const float*)d_in[2];
  const float* b1  = (const float*)d_in[3];
  const float* W1r = (const float*)d_in[4];
  const float* W2l = (const float*)d_in[5];
  const float* b2  = (const float*)d_in[6];
  const float* W2r = (const float*)d_in[7];
  float* out = (float*)d_out;

  char* ws = (char*)d_ws;
  float* h1pre = (float*)(ws + OFF_H1PRE);
  float* h1    = (float*)(ws + OFF_H1);
  float* m2    = (float*)(ws + OFF_M2);
  int*   deg   = (int*)(ws + OFF_DEG);
  int*   off   = (int*)(ws + OFF_OFFS);
  int*   cur   = (int*)(ws + OFF_CUR);
  int*   esrc  = (int*)(ws + OFF_ESRC);
  int*   bsum  = (int*)(ws + OFF_BSUM);
  int*   boff  = (int*)(ws + OFF_BOFF);

  hipMemsetAsync(deg, 0, N_NODES * sizeof(int), stream);

  k_gemm1<<<(N_NODES + 31) / 32, 256, 0, stream>>>(x, W1l, W1r, h1pre);

  k_hist<<<(N_EDGES + 255) / 256, 256, 0, stream>>>(ei, deg);
  k_scan_a<<<25, 256, 0, stream>>>(deg, off, bsum);
  k_scan_b<<<1, 64, 0, stream>>>(bsum, boff);
  k_scan_c<<<(N_NODES + 255) / 256, 256, 0, stream>>>(off, cur, boff);
  k_fill<<<(N_EDGES + 255) / 256, 256, 0, stream>>>(ei, cur, esrc);

  k_agg1<<<N_NODES / 4, 256, 0, stream>>>(h1pre, off, deg, esrc, b1, h1);
  k_gemm2<<<(N_NODES + 31) / 32, 256, 0, stream>>>(h1, W2l, W2r, m2);
  k_agg2<<<N_NODES / 8, 256, 0, stream>>>(m2, off, deg, esrc, b2, out);
}

// Round 2
// 580.419 us; speedup vs baseline: 1.5056x; 1.5056x over previous
//
#include <hip/hip_runtime.h>
#include <hip/hip_bf16.h>
#include <cstdint>
#include <cstddef>

// GraphSAGE 2-layer: h1 = mean_agg(x@W1_l) + b1 + x@W1_r ; h2 = mean_agg(h1@W2_l) + b2 + h1@W2_r
// out = log_softmax(relu(h2))
//
// Round 2: GEMM1 -> bf16 MFMA (16x16x32), fused fp32->bf16 cvt in staging,
// XOR-swizzled LDS tiles ((row&7)<<4 on byte addr) per G4. Weights pre-cast
// and transposed once into Wt[128][1472] bf16 (k-padded). Rest unchanged.

#define N_NODES 50000
#define N_EDGES 800000
#define F_IN    1433
#define KP      1472   // 23 * 64, zero-padded K

typedef __attribute__((ext_vector_type(8))) short bf16x8;
typedef __attribute__((ext_vector_type(4))) float f32x4;

// ---- workspace layout (bytes) ----
static constexpr size_t OFF_H1PRE = 0;                               // 50000*128*4 = 25,600,000
static constexpr size_t OFF_H1    = OFF_H1PRE + 25600000;            // 50000*64*4  = 12,800,000
static constexpr size_t OFF_M2    = OFF_H1    + 12800000;            // 50000*64*4  = 12,800,000
static constexpr size_t OFF_DEG   = OFF_M2    + 12800000;            // 50000*4
static constexpr size_t OFF_OFFS  = OFF_DEG   + 200000;              // 50000*4
static constexpr size_t OFF_CUR   = OFF_OFFS  + 200000;              // 50000*4
static constexpr size_t OFF_ESRC  = OFF_CUR   + 200000;              // 800000*4
static constexpr size_t OFF_BSUM  = OFF_ESRC  + 3200000;             // 25*4 (pad 256)
static constexpr size_t OFF_BOFF  = OFF_BSUM  + 256;                 // 25*4 (pad 256)
static constexpr size_t OFF_WT    = OFF_BOFF  + 256;                 // 128*1472*2 = 376,832

__device__ inline ushort f2bf(float f) {
  union { float f; uint32_t u; } v; v.f = f;
  uint32_t u = v.u + 0x7FFFu + ((v.u >> 16) & 1u);   // RNE
  return (ushort)(u >> 16);
}

// ---- weight prep: Wt[c][k] = c<64 ? W1l[k][c] : W1r[k][c-64], bf16, k-padded ----
__global__ __launch_bounds__(256) void k_prep_w(const float* __restrict__ Wl,
                                                const float* __restrict__ Wr,
                                                ushort* __restrict__ Wt) {
  const int c = blockIdx.x;                       // 0..127
  const int k = blockIdx.y * 256 + threadIdx.x;   // 0..1535
  if (k >= KP) return;
  float v = 0.f;
  if (k < F_IN) v = (c < 64) ? Wl[k * 64 + c] : Wr[k * 64 + (c - 64)];
  Wt[(size_t)c * KP + k] = f2bf(v);
}

// ---------------- GEMM1: MFMA bf16, BM=64 x BN=128, BK=64 ----------------
__global__ __launch_bounds__(256) void k_gemm1(const float* __restrict__ x,
                                               const ushort* __restrict__ Wt,
                                               float* __restrict__ h1pre) {
  __shared__ ushort As[64 * 64];    // [row][k] bf16, XOR-swizzled
  __shared__ ushort Bs[128 * 64];   // [outcol][k] bf16, XOR-swizzled
  const int t    = threadIdx.x;
  const int lane = t & 63;
  const int wid  = t >> 6;          // 0..3
  const int wr   = wid >> 1;        // wave row 0..1 (32 rows each)
  const int wc   = wid & 1;         // wave col 0..1 (64 cols each)
  const int row0 = blockIdx.x * 64;

  f32x4 acc[2][4] = {};

  for (int k0 = 0; k0 < KP; k0 += 64) {
    // ---- stage A: 64 rows x 64 k, fp32 -> bf16, coalesced scalar loads ----
#pragma unroll
    for (int i = 0; i < 16; ++i) {
      int idx = t + 256 * i;        // 0..4095
      int r = idx >> 6, k = idx & 63;
      int gr = row0 + r, gk = k0 + k;
      float v = 0.f;
      if (gr < N_NODES && gk < F_IN) v = x[(size_t)gr * F_IN + gk];
      int byte = (r * 128 + k * 2) ^ ((r & 7) << 4);
      *(ushort*)((char*)As + byte) = f2bf(v);
    }
    // ---- stage B: Wt 128 rows x 64 k bf16, dwordx4 loads ----
#pragma unroll
    for (int p = 0; p < 4; ++p) {
      int r  = p * 32 + (t >> 3);   // 0..127
      int k8 = (t & 7) * 8;
      uint4 v = *(const uint4*)(&Wt[(size_t)r * KP + k0 + k8]);
      int byte = (r * 128 + k8 * 2) ^ ((r & 7) << 4);
      *(uint4*)((char*)Bs + byte) = v;
    }
    __syncthreads();
#pragma unroll
    for (int kk = 0; kk < 2; ++kk) {
      bf16x8 a[2], b[4];
      const int kbyte = (kk * 32 + (lane >> 4) * 8) * 2;
#pragma unroll
      for (int m = 0; m < 2; ++m) {
        int r = wr * 32 + m * 16 + (lane & 15);
        int byte = (r * 128 + kbyte) ^ ((r & 7) << 4);
        a[m] = *(const bf16x8*)((const char*)As + byte);
      }
#pragma unroll
      for (int n = 0; n < 4; ++n) {
        int r = wc * 64 + n * 16 + (lane & 15);
        int byte = (r * 128 + kbyte) ^ ((r & 7) << 4);
        b[n] = *(const bf16x8*)((const char*)Bs + byte);
      }
#pragma unroll
      for (int m = 0; m < 2; ++m)
#pragma unroll
        for (int n = 0; n < 4; ++n)
          acc[m][n] = __builtin_amdgcn_mfma_f32_16x16x32_bf16(a[m], b[n], acc[m][n], 0, 0, 0);
    }
    __syncthreads();
  }

  // epilogue: D frag (m,n): row = (lane>>4)*4 + reg, col = lane&15
#pragma unroll
  for (int m = 0; m < 2; ++m) {
    int rbase = row0 + wr * 32 + m * 16 + (lane >> 4) * 4;
#pragma unroll
    for (int n = 0; n < 4; ++n) {
      int col = wc * 64 + n * 16 + (lane & 15);
#pragma unroll
      for (int r = 0; r < 4; ++r) {
        int grow = rbase + r;
        if (grow < N_NODES) h1pre[(size_t)grow * 128 + col] = acc[m][n][r];
      }
    }
  }
}

// ---------------- CSR build ----------------
__global__ void k_hist(const int* __restrict__ ei, int* __restrict__ deg) {
  int e = blockIdx.x * blockDim.x + threadIdx.x;
  if (e < N_EDGES) atomicAdd(&deg[ei[N_EDGES + e]], 1);
}

__global__ __launch_bounds__(256) void k_scan_a(const int* __restrict__ deg,
                                                int* __restrict__ off,
                                                int* __restrict__ blksum) {
  __shared__ int sd[256];
  const int t = threadIdx.x;
  const int base = blockIdx.x * 2048 + t * 8;
  int v[8];
  int s = 0;
#pragma unroll
  for (int j = 0; j < 8; ++j) {
    int i = base + j;
    v[j] = (i < N_NODES) ? deg[i] : 0;
    s += v[j];
  }
  sd[t] = s;
  __syncthreads();
  for (int o = 1; o < 256; o <<= 1) {
    int u = (t >= o) ? sd[t - o] : 0;
    __syncthreads();
    sd[t] += u;
    __syncthreads();
  }
  int excl = sd[t] - s;
#pragma unroll
  for (int j = 0; j < 8; ++j) {
    int i = base + j;
    if (i < N_NODES) off[i] = excl;
    excl += v[j];
  }
  if (t == 255) blksum[blockIdx.x] = sd[255];
}

__global__ void k_scan_b(const int* __restrict__ blksum, int* __restrict__ blkoff) {
  if (threadIdx.x == 0) {
    int run = 0;
    for (int i = 0; i < 25; ++i) { blkoff[i] = run; run += blksum[i]; }
  }
}

__global__ void k_scan_c(int* __restrict__ off, int* __restrict__ cur,
                         const int* __restrict__ blkoff) {
  int i = blockIdx.x * blockDim.x + threadIdx.x;
  if (i < N_NODES) {
    int v = off[i] + blkoff[i >> 11];
    off[i] = v;
    cur[i] = v;
  }
}

__global__ void k_fill(const int* __restrict__ ei, int* __restrict__ cur,
                       int* __restrict__ esrc) {
  int e = blockIdx.x * blockDim.x + threadIdx.x;
  if (e < N_EDGES) {
    int s = ei[e];
    int d = ei[N_EDGES + e];
    int slot = atomicAdd(&cur[d], 1);
    esrc[slot] = s;
  }
}

// ---------------- aggregate layer 1: one wave (64 lanes = 64 feats) per dst ----------------
__global__ __launch_bounds__(256) void k_agg1(const float* __restrict__ h1pre,
                                              const int* __restrict__ off,
                                              const int* __restrict__ deg,
                                              const int* __restrict__ esrc,
                                              const float* __restrict__ b1,
                                              float* __restrict__ h1) {
  const int lane = threadIdx.x & 63;
  const int d = blockIdx.x * 4 + (threadIdx.x >> 6);
  if (d >= N_NODES) return;
  const int dg = deg[d];
  const int base = off[d];
  float acc = 0.f;
  for (int j = 0; j < dg; ++j) {
    int s = esrc[base + j];
    acc += h1pre[(size_t)s * 128 + lane];
  }
  const float inv = (dg > 0) ? 1.f / (float)dg : 0.f;
  h1[(size_t)d * 64 + lane] = acc * inv + b1[lane] + h1pre[(size_t)d * 128 + 64 + lane];
}

// ---------------- GEMM2: h1[50000,64] @ [W2_l|W2_r][64,64] -> m2[50000,64] ----------------
__global__ __launch_bounds__(256) void k_gemm2(const float* __restrict__ h1,
                                               const float* __restrict__ W2l,
                                               const float* __restrict__ W2r,
                                               float* __restrict__ m2) {
  __shared__ __align__(16) float Ws[64][68];
  __shared__ __align__(16) float Hs[32][68];
  const int t = threadIdx.x;
#pragma unroll
  for (int i = 0; i < 16; ++i) {
    int idx = t + 256 * i;          // 0..4095
    int k = idx >> 6, c = idx & 63;
    Ws[k][c] = (c < 32) ? W2l[k * 32 + c] : W2r[k * 32 + (c - 32)];
  }
  const int r0 = blockIdx.x * 32;
#pragma unroll
  for (int i = 0; i < 8; ++i) {
    int idx = t + 256 * i;          // 0..2047
    int r = idx >> 6, c = idx & 63;
    int gr = r0 + r;
    Hs[r][c] = (gr < N_NODES) ? h1[(size_t)gr * 64 + c] : 0.f;
  }
  __syncthreads();
  const int rl = t >> 3;            // 0..31
  const int c0 = (t & 7) * 8;       // 0,8,..,56
  float acc[8] = {};
#pragma unroll 8
  for (int k = 0; k < 64; ++k) {
    float hv = Hs[rl][k];
#pragma unroll
    for (int j = 0; j < 8; ++j) acc[j] = fmaf(hv, Ws[k][c0 + j], acc[j]);
  }
  const int gr = r0 + rl;
  if (gr < N_NODES) {
    *(float4*)(&m2[(size_t)gr * 64 + c0])     = make_float4(acc[0], acc[1], acc[2], acc[3]);
    *(float4*)(&m2[(size_t)gr * 64 + c0 + 4]) = make_float4(acc[4], acc[5], acc[6], acc[7]);
  }
}

// ---------------- aggregate layer 2 + relu + log_softmax: half-wave (32 lanes) per dst ----------------
__global__ __launch_bounds__(256) void k_agg2(const float* __restrict__ m2,
                                              const int* __restrict__ off,
                                              const int* __restrict__ deg,
                                              const int* __restrict__ esrc,
                                              const float* __restrict__ b2,
                                              float* __restrict__ out) {
  const int lane = threadIdx.x & 63;
  const int half = lane >> 5;
  const int f = lane & 31;
  const int d = blockIdx.x * 8 + ((threadIdx.x >> 6) << 1) + half;  // 50000 % 8 == 0
  const int dg = deg[d];
  const int base = off[d];
  float acc = 0.f;
  for (int j = 0; j < dg; ++j) {
    int s = esrc[base + j];
    acc += m2[(size_t)s * 64 + f];
  }
  const float inv = (dg > 0) ? 1.f / (float)dg : 0.f;
  float v = acc * inv + b2[f] + m2[(size_t)d * 64 + 32 + f];
  v = fmaxf(v, 0.f);
  float m = v;
#pragma unroll
  for (int o = 16; o > 0; o >>= 1) m = fmaxf(m, __shfl_xor(m, o, 32));
  float e = expf(v - m);
  float sum = e;
#pragma unroll
  for (int o = 16; o > 0; o >>= 1) sum += __shfl_xor(sum, o, 32);
  out[(size_t)d * 32 + f] = v - m - logf(sum);
}

extern "C" void kernel_launch(void* const* d_in, const int* in_sizes, int n_in,
                              void* d_out, int out_size, void* d_ws, size_t ws_size,
                              hipStream_t stream) {
  const float* x   = (const float*)d_in[0];
  const int*   ei  = (const int*)d_in[1];
  const float* W1l = (const float*)d_in[2];
  const float* b1  = (const float*)d_in[3];
  const float* W1r = (const float*)d_in[4];
  const float* W2l = (const float*)d_in[5];
  const float* b2  = (const float*)d_in[6];
  const float* W2r = (const float*)d_in[7];
  float* out = (float*)d_out;

  char* ws = (char*)d_ws;
  float*  h1pre = (float*)(ws + OFF_H1PRE);
  float*  h1    = (float*)(ws + OFF_H1);
  float*  m2    = (float*)(ws + OFF_M2);
  int*    deg   = (int*)(ws + OFF_DEG);
  int*    off   = (int*)(ws + OFF_OFFS);
  int*    cur   = (int*)(ws + OFF_CUR);
  int*    esrc  = (int*)(ws + OFF_ESRC);
  int*    bsum  = (int*)(ws + OFF_BSUM);
  int*    boff  = (int*)(ws + OFF_BOFF);
  ushort* Wt    = (ushort*)(ws + OFF_WT);

  hipMemsetAsync(deg, 0, N_NODES * sizeof(int), stream);

  {
    dim3 g(128, (KP + 255) / 256);
    k_prep_w<<<g, 256, 0, stream>>>(W1l, W1r, Wt);
  }
  k_gemm1<<<(N_NODES + 63) / 64, 256, 0, stream>>>(x, Wt, h1pre);

  k_hist<<<(N_EDGES + 255) / 256, 256, 0, stream>>>(ei, deg);
  k_scan_a<<<25, 256, 0, stream>>>(deg, off, bsum);
  k_scan_b<<<1, 64, 0, stream>>>(bsum, boff);
  k_scan_c<<<(N_NODES + 255) / 256, 256, 0, stream>>>(off, cur, boff);
  k_fill<<<(N_EDGES + 255) / 256, 256, 0, stream>>>(ei, cur, esrc);

  k_agg1<<<N_NODES / 4, 256, 0, stream>>>(h1pre, off, deg, esrc, b1, h1);
  k_gemm2<<<(N_NODES + 31) / 32, 256, 0, stream>>>(h1, W2l, W2r, m2);
  k_agg2<<<N_NODES / 8, 256, 0, stream>>>(m2, off, deg, esrc, b2, out);
}

// Round 3
// 394.434 us; speedup vs baseline: 2.2155x; 1.4715x over previous
//
#include <hip/hip_runtime.h>
#include <hip/hip_bf16.h>
#include <cstdint>
#include <cstddef>

// GraphSAGE 2-layer: h1 = mean_agg(x@W1_l) + b1 + x@W1_r ; h2 = mean_agg(h1@W2_l) + b2 + h1@W2_r
// out = log_softmax(relu(h2))
//
// Round 3: x -> bf16 streaming cvt pass, then GEMM1 = m97-structure MFMA:
// global_load_lds width 16 (linear LDS dest, inverse-swizzled global source),
// XOR-swizzled ds_read_b128 fragment reads, 2-phase LDS double-buffer.
// Fallback to round-2 fp32-read GEMM if ws_size can't hold x_bf.

#define N_NODES 50000
#define N_EDGES 800000
#define F_IN    1433
#define KP      1472   // 23 * 64, zero-padded K
#define NKT     23     // K tiles of 64

typedef __attribute__((ext_vector_type(8))) short bf16x8;
typedef __attribute__((ext_vector_type(4))) float f32x4;

// ---- workspace layout (bytes) ----
static constexpr size_t OFF_H1PRE = 0;                               // 50000*128*4 = 25,600,000
static constexpr size_t OFF_H1    = OFF_H1PRE + 25600000;            // 50000*64*4  = 12,800,000
static constexpr size_t OFF_M2    = OFF_H1    + 12800000;            // 50000*64*4  = 12,800,000
static constexpr size_t OFF_DEG   = OFF_M2    + 12800000;            // 50000*4
static constexpr size_t OFF_OFFS  = OFF_DEG   + 200000;              // 50000*4
static constexpr size_t OFF_CUR   = OFF_OFFS  + 200000;              // 50000*4
static constexpr size_t OFF_ESRC  = OFF_CUR   + 200000;              // 800000*4
static constexpr size_t OFF_BSUM  = OFF_ESRC  + 3200000;             // 25*4 (pad 256)
static constexpr size_t OFF_BOFF  = OFF_BSUM  + 256;                 // 25*4 (pad 256)
static constexpr size_t OFF_WT    = OFF_BOFF  + 256;                 // 128*1472*2 = 376,832
static constexpr size_t OFF_XBF   = OFF_WT    + 376832;              // 50000*1472*2 = 147,200,000
static constexpr size_t XBF_BYTES = (size_t)N_NODES * KP * 2;

__device__ inline ushort f2bf(float f) {
  union { float f; uint32_t u; } v; v.f = f;
  uint32_t u = v.u + 0x7FFFu + ((v.u >> 16) & 1u);   // RNE
  return (ushort)(u >> 16);
}

__device__ __forceinline__ void gload_lds16(const void* g, void* l) {
  __builtin_amdgcn_global_load_lds(
      (const __attribute__((address_space(1))) void*)g,
      (__attribute__((address_space(3))) void*)l, 16, 0, 0);
}

// ---- weight prep: Wt[c][k] = c<64 ? W1l[k][c] : W1r[k][c-64], bf16, k-padded ----
__global__ __launch_bounds__(256) void k_prep_w(const float* __restrict__ Wl,
                                                const float* __restrict__ Wr,
                                                ushort* __restrict__ Wt) {
  const int c = blockIdx.x;                       // 0..127
  const int k = blockIdx.y * 256 + threadIdx.x;
  if (k >= KP) return;
  float v = 0.f;
  if (k < F_IN) v = (c < 64) ? Wl[k * 64 + c] : Wr[k * 64 + (c - 64)];
  Wt[(size_t)c * KP + k] = f2bf(v);
}

// ---- x fp32 -> x_bf bf16 (row-padded to KP), one row per block ----
__global__ __launch_bounds__(256) void k_cvt(const float* __restrict__ x,
                                             ushort* __restrict__ xbf) {
  const int r = blockIdx.x;
  const float* xr = x + (size_t)r * F_IN;
  uint32_t* orow = (uint32_t*)(xbf + (size_t)r * KP);
#pragma unroll
  for (int i = 0; i < 3; ++i) {
    int p = threadIdx.x + i * 256;     // dword pair index, 736 per row
    if (p < KP / 2) {
      int c0 = 2 * p, c1 = 2 * p + 1;
      float v0 = (c0 < F_IN) ? xr[c0] : 0.f;
      float v1 = (c1 < F_IN) ? xr[c1] : 0.f;
      orow[p] = (uint32_t)f2bf(v0) | ((uint32_t)f2bf(v1) << 16);
    }
  }
}

// ---------------- GEMM1 (bf16 MFMA): BM=64, BN=128, BK=64, dbuf ----------------
// LDS tiles store logical (row r, 16B k-slot s) at physical slot s^(r&7).
// global_load_lds writes linearly (base + lane*16) => pre-swizzle the SOURCE.
__global__ __launch_bounds__(256) void k_gemm1_bf(const ushort* __restrict__ xbf,
                                                  const ushort* __restrict__ Wt,
                                                  float* __restrict__ h1pre) {
  __shared__ ushort As[2][64 * 64];    // 8 KB per buf
  __shared__ ushort Bs[2][128 * 64];   // 16 KB per buf
  const int t    = threadIdx.x;
  const int lane = t & 63;
  const int w    = t >> 6;             // 0..3
  const int wr   = w >> 1;
  const int wc   = w & 1;
  const int row0 = blockIdx.x * 64;
  const int lr   = lane >> 3;          // 0..7 (row within 8-row stripe)
  const int lt   = lane & 7;           // 0..7 (16B slot)

  f32x4 acc[2][4] = {};

  // per-lane invariants for staging
  int a_r[2], a_sl[2]; const ushort* a_src[2];
  ushort* a_dst[2];
#pragma unroll
  for (int i = 0; i < 2; ++i) {
    int r = (w * 2 + i) * 8 + lr;                 // 0..63
    int gr = row0 + r; if (gr > N_NODES - 1) gr = N_NODES - 1;
    a_r[i] = r; a_sl[i] = (lt ^ (r & 7)) * 8;
    a_src[i] = xbf + (size_t)gr * KP + a_sl[i];
    a_dst[i] = (ushort*)&As[0][(w * 2 + i) * 512];
  }
  int b_sl[4]; const ushort* b_src[4]; ushort* b_dst[4];
#pragma unroll
  for (int j = 0; j < 4; ++j) {
    int r = (w * 4 + j) * 8 + lr;                 // 0..127
    b_sl[j] = (lt ^ (r & 7)) * 8;
    b_src[j] = Wt + (size_t)r * KP + b_sl[j];
    b_dst[j] = (ushort*)&Bs[0][(w * 4 + j) * 512];
  }
  const size_t bufstride_a = 64 * 64;   // ushorts
  const size_t bufstride_b = 128 * 64;

#define STAGE(buf, k0)                                                        \
  do {                                                                        \
    _Pragma("unroll")                                                         \
    for (int i = 0; i < 2; ++i)                                               \
      gload_lds16(a_src[i] + (k0), a_dst[i] + (size_t)(buf) * bufstride_a);   \
    _Pragma("unroll")                                                         \
    for (int j = 0; j < 4; ++j)                                               \
      gload_lds16(b_src[j] + (k0), b_dst[j] + (size_t)(buf) * bufstride_b);   \
  } while (0)

  int cur = 0;
  STAGE(0, 0);
  __syncthreads();

  for (int kt = 0; kt < NKT; ++kt) {
    if (kt + 1 < NKT) STAGE(cur ^ 1, (kt + 1) * 64);
#pragma unroll
    for (int kk = 0; kk < 2; ++kk) {
      bf16x8 a[2], b[4];
      const int sbase = kk * 4 + (lane >> 4);     // logical slot 0..7
#pragma unroll
      for (int m = 0; m < 2; ++m) {
        int r = wr * 32 + m * 16 + (lane & 15);
        int s = sbase ^ (r & 7);
        a[m] = *(const bf16x8*)&As[cur][r * 64 + s * 8];
      }
#pragma unroll
      for (int n = 0; n < 4; ++n) {
        int r = wc * 64 + n * 16 + (lane & 15);
        int s = sbase ^ (r & 7);
        b[n] = *(const bf16x8*)&Bs[cur][r * 64 + s * 8];
      }
#pragma unroll
      for (int m = 0; m < 2; ++m)
#pragma unroll
        for (int n = 0; n < 4; ++n)
          acc[m][n] = __builtin_amdgcn_mfma_f32_16x16x32_bf16(a[m], b[n], acc[m][n], 0, 0, 0);
    }
    __syncthreads();
    cur ^= 1;
  }
#undef STAGE

  // epilogue: D frag (m,n): row = (lane>>4)*4 + reg, col = lane&15
#pragma unroll
  for (int m = 0; m < 2; ++m) {
    int rbase = row0 + wr * 32 + m * 16 + (lane >> 4) * 4;
#pragma unroll
    for (int n = 0; n < 4; ++n) {
      int col = wc * 64 + n * 16 + (lane & 15);
#pragma unroll
      for (int r = 0; r < 4; ++r) {
        int grow = rbase + r;
        if (grow < N_NODES) h1pre[(size_t)grow * 128 + col] = acc[m][n][r];
      }
    }
  }
}

// ---------------- fallback GEMM1 (fp32 read, round-2 path) ----------------
__global__ __launch_bounds__(256) void k_gemm1_fp32(const float* __restrict__ x,
                                                    const ushort* __restrict__ Wt,
                                                    float* __restrict__ h1pre) {
  __shared__ ushort As[64 * 64];
  __shared__ ushort Bs[128 * 64];
  const int t    = threadIdx.x;
  const int lane = t & 63;
  const int wid  = t >> 6;
  const int wr   = wid >> 1;
  const int wc   = wid & 1;
  const int row0 = blockIdx.x * 64;
  f32x4 acc[2][4] = {};

  for (int k0 = 0; k0 < KP; k0 += 64) {
#pragma unroll
    for (int i = 0; i < 16; ++i) {
      int idx = t + 256 * i;
      int r = idx >> 6, k = idx & 63;
      int gr = row0 + r, gk = k0 + k;
      float v = 0.f;
      if (gr < N_NODES && gk < F_IN) v = x[(size_t)gr * F_IN + gk];
      int byte = (r * 128 + k * 2) ^ ((r & 7) << 4);
      *(ushort*)((char*)As + byte) = f2bf(v);
    }
#pragma unroll
    for (int p = 0; p < 4; ++p) {
      int r  = p * 32 + (t >> 3);
      int k8 = (t & 7) * 8;
      uint4 v = *(const uint4*)(&Wt[(size_t)r * KP + k0 + k8]);
      int byte = (r * 128 + k8 * 2) ^ ((r & 7) << 4);
      *(uint4*)((char*)Bs + byte) = v;
    }
    __syncthreads();
#pragma unroll
    for (int kk = 0; kk < 2; ++kk) {
      bf16x8 a[2], b[4];
      const int kbyte = (kk * 32 + (lane >> 4) * 8) * 2;
#pragma unroll
      for (int m = 0; m < 2; ++m) {
        int r = wr * 32 + m * 16 + (lane & 15);
        int byte = (r * 128 + kbyte) ^ ((r & 7) << 4);
        a[m] = *(const bf16x8*)((const char*)As + byte);
      }
#pragma unroll
      for (int n = 0; n < 4; ++n) {
        int r = wc * 64 + n * 16 + (lane & 15);
        int byte = (r * 128 + kbyte) ^ ((r & 7) << 4);
        b[n] = *(const bf16x8*)((const char*)Bs + byte);
      }
#pragma unroll
      for (int m = 0; m < 2; ++m)
#pragma unroll
        for (int n = 0; n < 4; ++n)
          acc[m][n] = __builtin_amdgcn_mfma_f32_16x16x32_bf16(a[m], b[n], acc[m][n], 0, 0, 0);
    }
    __syncthreads();
  }
#pragma unroll
  for (int m = 0; m < 2; ++m) {
    int rbase = row0 + wr * 32 + m * 16 + (lane >> 4) * 4;
#pragma unroll
    for (int n = 0; n < 4; ++n) {
      int col = wc * 64 + n * 16 + (lane & 15);
#pragma unroll
      for (int r = 0; r < 4; ++r) {
        int grow = rbase + r;
        if (grow < N_NODES) h1pre[(size_t)grow * 128 + col] = acc[m][n][r];
      }
    }
  }
}

// ---------------- CSR build ----------------
__global__ void k_hist(const int* __restrict__ ei, int* __restrict__ deg) {
  int e = blockIdx.x * blockDim.x + threadIdx.x;
  if (e < N_EDGES) atomicAdd(&deg[ei[N_EDGES + e]], 1);
}

__global__ __launch_bounds__(256) void k_scan_a(const int* __restrict__ deg,
                                                int* __restrict__ off,
                                                int* __restrict__ blksum) {
  __shared__ int sd[256];
  const int t = threadIdx.x;
  const int base = blockIdx.x * 2048 + t * 8;
  int v[8];
  int s = 0;
#pragma unroll
  for (int j = 0; j < 8; ++j) {
    int i = base + j;
    v[j] = (i < N_NODES) ? deg[i] : 0;
    s += v[j];
  }
  sd[t] = s;
  __syncthreads();
  for (int o = 1; o < 256; o <<= 1) {
    int u = (t >= o) ? sd[t - o] : 0;
    __syncthreads();
    sd[t] += u;
    __syncthreads();
  }
  int excl = sd[t] - s;
#pragma unroll
  for (int j = 0; j < 8; ++j) {
    int i = base + j;
    if (i < N_NODES) off[i] = excl;
    excl += v[j];
  }
  if (t == 255) blksum[blockIdx.x] = sd[255];
}

__global__ void k_scan_b(const int* __restrict__ blksum, int* __restrict__ blkoff) {
  if (threadIdx.x == 0) {
    int run = 0;
    for (int i = 0; i < 25; ++i) { blkoff[i] = run; run += blksum[i]; }
  }
}

__global__ void k_scan_c(int* __restrict__ off, int* __restrict__ cur,
                         const int* __restrict__ blkoff) {
  int i = blockIdx.x * blockDim.x + threadIdx.x;
  if (i < N_NODES) {
    int v = off[i] + blkoff[i >> 11];
    off[i] = v;
    cur[i] = v;
  }
}

__global__ void k_fill(const int* __restrict__ ei, int* __restrict__ cur,
                       int* __restrict__ esrc) {
  int e = blockIdx.x * blockDim.x + threadIdx.x;
  if (e < N_EDGES) {
    int s = ei[e];
    int d = ei[N_EDGES + e];
    int slot = atomicAdd(&cur[d], 1);
    esrc[slot] = s;
  }
}

// ---------------- aggregate layer 1: one wave (64 lanes = 64 feats) per dst ----------------
__global__ __launch_bounds__(256) void k_agg1(const float* __restrict__ h1pre,
                                              const int* __restrict__ off,
                                              const int* __restrict__ deg,
                                              const int* __restrict__ esrc,
                                              const float* __restrict__ b1,
                                              float* __restrict__ h1) {
  const int lane = threadIdx.x & 63;
  const int d = blockIdx.x * 4 + (threadIdx.x >> 6);
  if (d >= N_NODES) return;
  const int dg = deg[d];
  const int base = off[d];
  float acc = 0.f;
  for (int j = 0; j < dg; ++j) {
    int s = esrc[base + j];
    acc += h1pre[(size_t)s * 128 + lane];
  }
  const float inv = (dg > 0) ? 1.f / (float)dg : 0.f;
  h1[(size_t)d * 64 + lane] = acc * inv + b1[lane] + h1pre[(size_t)d * 128 + 64 + lane];
}

// ---------------- GEMM2: h1[50000,64] @ [W2_l|W2_r][64,64] -> m2[50000,64] ----------------
__global__ __launch_bounds__(256) void k_gemm2(const float* __restrict__ h1,
                                               const float* __restrict__ W2l,
                                               const float* __restrict__ W2r,
                                               float* __restrict__ m2) {
  __shared__ __align__(16) float Ws[64][68];
  __shared__ __align__(16) float Hs[32][68];
  const int t = threadIdx.x;
#pragma unroll
  for (int i = 0; i < 16; ++i) {
    int idx = t + 256 * i;
    int k = idx >> 6, c = idx & 63;
    Ws[k][c] = (c < 32) ? W2l[k * 32 + c] : W2r[k * 32 + (c - 32)];
  }
  const int r0 = blockIdx.x * 32;
#pragma unroll
  for (int i = 0; i < 8; ++i) {
    int idx = t + 256 * i;
    int r = idx >> 6, c = idx & 63;
    int gr = r0 + r;
    Hs[r][c] = (gr < N_NODES) ? h1[(size_t)gr * 64 + c] : 0.f;
  }
  __syncthreads();
  const int rl = t >> 3;
  const int c0 = (t & 7) * 8;
  float acc[8] = {};
#pragma unroll 8
  for (int k = 0; k < 64; ++k) {
    float hv = Hs[rl][k];
#pragma unroll
    for (int j = 0; j < 8; ++j) acc[j] = fmaf(hv, Ws[k][c0 + j], acc[j]);
  }
  const int gr = r0 + rl;
  if (gr < N_NODES) {
    *(float4*)(&m2[(size_t)gr * 64 + c0])     = make_float4(acc[0], acc[1], acc[2], acc[3]);
    *(float4*)(&m2[(size_t)gr * 64 + c0 + 4]) = make_float4(acc[4], acc[5], acc[6], acc[7]);
  }
}

// ---------------- aggregate layer 2 + relu + log_softmax ----------------
__global__ __launch_bounds__(256) void k_agg2(const float* __restrict__ m2,
                                              const int* __restrict__ off,
                                              const int* __restrict__ deg,
                                              const int* __restrict__ esrc,
                                              const float* __restrict__ b2,
                                              float* __restrict__ out) {
  const int lane = threadIdx.x & 63;
  const int half = lane >> 5;
  const int f = lane & 31;
  const int d = blockIdx.x * 8 + ((threadIdx.x >> 6) << 1) + half;  // 50000 % 8 == 0
  const int dg = deg[d];
  const int base = off[d];
  float acc = 0.f;
  for (int j = 0; j < dg; ++j) {
    int s = esrc[base + j];
    acc += m2[(size_t)s * 64 + f];
  }
  const float inv = (dg > 0) ? 1.f / (float)dg : 0.f;
  float v = acc * inv + b2[f] + m2[(size_t)d * 64 + 32 + f];
  v = fmaxf(v, 0.f);
  float m = v;
#pragma unroll
  for (int o = 16; o > 0; o >>= 1) m = fmaxf(m, __shfl_xor(m, o, 32));
  float e = expf(v - m);
  float sum = e;
#pragma unroll
  for (int o = 16; o > 0; o >>= 1) sum += __shfl_xor(sum, o, 32);
  out[(size_t)d * 32 + f] = v - m - logf(sum);
}

extern "C" void kernel_launch(void* const* d_in, const int* in_sizes, int n_in,
                              void* d_out, int out_size, void* d_ws, size_t ws_size,
                              hipStream_t stream) {
  const float* x   = (const float*)d_in[0];
  const int*   ei  = (const int*)d_in[1];
  const float* W1l = (const float*)d_in[2];
  const float* b1  = (const float*)d_in[3];
  const float* W1r = (const float*)d_in[4];
  const float* W2l = (const float*)d_in[5];
  const float* b2  = (const float*)d_in[6];
  const float* W2r = (const float*)d_in[7];
  float* out = (float*)d_out;

  char* ws = (char*)d_ws;
  float*  h1pre = (float*)(ws + OFF_H1PRE);
  float*  h1    = (float*)(ws + OFF_H1);
  float*  m2    = (float*)(ws + OFF_M2);
  int*    deg   = (int*)(ws + OFF_DEG);
  int*    off   = (int*)(ws + OFF_OFFS);
  int*    cur   = (int*)(ws + OFF_CUR);
  int*    esrc  = (int*)(ws + OFF_ESRC);
  int*    bsum  = (int*)(ws + OFF_BSUM);
  int*    boff  = (int*)(ws + OFF_BOFF);
  ushort* Wt    = (ushort*)(ws + OFF_WT);
  ushort* xbf   = (ushort*)(ws + OFF_XBF);

  const bool big = ws_size >= OFF_XBF + XBF_BYTES;

  hipMemsetAsync(deg, 0, N_NODES * sizeof(int), stream);

  {
    dim3 g(128, (KP + 255) / 256);
    k_prep_w<<<g, 256, 0, stream>>>(W1l, W1r, Wt);
  }
  if (big) {
    k_cvt<<<N_NODES, 256, 0, stream>>>(x, xbf);
    k_gemm1_bf<<<(N_NODES + 63) / 64, 256, 0, stream>>>(xbf, Wt, h1pre);
  } else {
    k_gemm1_fp32<<<(N_NODES + 63) / 64, 256, 0, stream>>>(x, Wt, h1pre);
  }

  k_hist<<<(N_EDGES + 255) / 256, 256, 0, stream>>>(ei, deg);
  k_scan_a<<<25, 256, 0, stream>>>(deg, off, bsum);
  k_scan_b<<<1, 64, 0, stream>>>(bsum, boff);
  k_scan_c<<<(N_NODES + 255) / 256, 256, 0, stream>>>(off, cur, boff);
  k_fill<<<(N_EDGES + 255) / 256, 256, 0, stream>>>(ei, cur, esrc);

  k_agg1<<<N_NODES / 4, 256, 0, stream>>>(h1pre, off, deg, esrc, b1, h1);
  k_gemm2<<<(N_NODES + 31) / 32, 256, 0, stream>>>(h1, W2l, W2r, m2);
  k_agg2<<<N_NODES / 8, 256, 0, stream>>>(m2, off, deg, esrc, b2, out);
}

// Round 4
// 390.757 us; speedup vs baseline: 2.2363x; 1.0094x over previous
//
#include <hip/hip_runtime.h>
#include <hip/hip_bf16.h>
#include <cstdint>
#include <cstddef>

// GraphSAGE 2-layer: h1 = mean_agg(x@W1_l) + b1 + x@W1_r ; h2 = mean_agg(h1@W2_l) + b2 + h1@W2_r
// out = log_softmax(relu(h2))
//
// Round 4: replace hipMemsetAsync(deg) with k_zero_deg — rocprof showed the
// runtime fillBufferAligned for the 200 KB memset costing ~170 us per replay
// (43% of total). Rest identical to round 3.

#define N_NODES 50000
#define N_EDGES 800000
#define F_IN    1433
#define KP      1472   // 23 * 64, zero-padded K
#define NKT     23     // K tiles of 64

typedef __attribute__((ext_vector_type(8))) short bf16x8;
typedef __attribute__((ext_vector_type(4))) float f32x4;

// ---- workspace layout (bytes) ----
static constexpr size_t OFF_H1PRE = 0;                               // 50000*128*4 = 25,600,000
static constexpr size_t OFF_H1    = OFF_H1PRE + 25600000;            // 50000*64*4  = 12,800,000
static constexpr size_t OFF_M2    = OFF_H1    + 12800000;            // 50000*64*4  = 12,800,000
static constexpr size_t OFF_DEG   = OFF_M2    + 12800000;            // 50000*4
static constexpr size_t OFF_OFFS  = OFF_DEG   + 200000;              // 50000*4
static constexpr size_t OFF_CUR   = OFF_OFFS  + 200000;              // 50000*4
static constexpr size_t OFF_ESRC  = OFF_CUR   + 200000;              // 800000*4
static constexpr size_t OFF_BSUM  = OFF_ESRC  + 3200000;             // 25*4 (pad 256)
static constexpr size_t OFF_BOFF  = OFF_BSUM  + 256;                 // 25*4 (pad 256)
static constexpr size_t OFF_WT    = OFF_BOFF  + 256;                 // 128*1472*2 = 376,832
static constexpr size_t OFF_XBF   = OFF_WT    + 376832;              // 50000*1472*2 = 147,200,000
static constexpr size_t XBF_BYTES = (size_t)N_NODES * KP * 2;

__device__ inline ushort f2bf(float f) {
  union { float f; uint32_t u; } v; v.f = f;
  uint32_t u = v.u + 0x7FFFu + ((v.u >> 16) & 1u);   // RNE
  return (ushort)(u >> 16);
}

__device__ __forceinline__ void gload_lds16(const void* g, void* l) {
  __builtin_amdgcn_global_load_lds(
      (const __attribute__((address_space(1))) void*)g,
      (__attribute__((address_space(3))) void*)l, 16, 0, 0);
}

// ---- zero deg (replaces pathological runtime fillBufferAligned) ----
__global__ __launch_bounds__(256) void k_zero_deg(int* __restrict__ deg) {
  int i = blockIdx.x * 256 + threadIdx.x;
  if (i < N_NODES) deg[i] = 0;
}

// ---- weight prep: Wt[c][k] = c<64 ? W1l[k][c] : W1r[k][c-64], bf16, k-padded ----
__global__ __launch_bounds__(256) void k_prep_w(const float* __restrict__ Wl,
                                                const float* __restrict__ Wr,
                                                ushort* __restrict__ Wt) {
  const int c = blockIdx.x;                       // 0..127
  const int k = blockIdx.y * 256 + threadIdx.x;
  if (k >= KP) return;
  float v = 0.f;
  if (k < F_IN) v = (c < 64) ? Wl[k * 64 + c] : Wr[k * 64 + (c - 64)];
  Wt[(size_t)c * KP + k] = f2bf(v);
}

// ---- x fp32 -> x_bf bf16 (row-padded to KP), one row per block ----
__global__ __launch_bounds__(256) void k_cvt(const float* __restrict__ x,
                                             ushort* __restrict__ xbf) {
  const int r = blockIdx.x;
  const float* xr = x + (size_t)r * F_IN;
  uint32_t* orow = (uint32_t*)(xbf + (size_t)r * KP);
#pragma unroll
  for (int i = 0; i < 3; ++i) {
    int p = threadIdx.x + i * 256;     // dword pair index, 736 per row
    if (p < KP / 2) {
      int c0 = 2 * p, c1 = 2 * p + 1;
      float v0 = (c0 < F_IN) ? xr[c0] : 0.f;
      float v1 = (c1 < F_IN) ? xr[c1] : 0.f;
      orow[p] = (uint32_t)f2bf(v0) | ((uint32_t)f2bf(v1) << 16);
    }
  }
}

// ---------------- GEMM1 (bf16 MFMA): BM=64, BN=128, BK=64, dbuf ----------------
// LDS tiles store logical (row r, 16B k-slot s) at physical slot s^(r&7).
// global_load_lds writes linearly (base + lane*16) => pre-swizzle the SOURCE.
__global__ __launch_bounds__(256) void k_gemm1_bf(const ushort* __restrict__ xbf,
                                                  const ushort* __restrict__ Wt,
                                                  float* __restrict__ h1pre) {
  __shared__ ushort As[2][64 * 64];    // 8 KB per buf
  __shared__ ushort Bs[2][128 * 64];   // 16 KB per buf
  const int t    = threadIdx.x;
  const int lane = t & 63;
  const int w    = t >> 6;             // 0..3
  const int wr   = w >> 1;
  const int wc   = w & 1;
  const int row0 = blockIdx.x * 64;
  const int lr   = lane >> 3;          // 0..7 (row within 8-row stripe)
  const int lt   = lane & 7;           // 0..7 (16B slot)

  f32x4 acc[2][4] = {};

  // per-lane invariants for staging
  int a_sl[2]; const ushort* a_src[2];
  ushort* a_dst[2];
#pragma unroll
  for (int i = 0; i < 2; ++i) {
    int r = (w * 2 + i) * 8 + lr;                 // 0..63
    int gr = row0 + r; if (gr > N_NODES - 1) gr = N_NODES - 1;
    a_sl[i] = (lt ^ (r & 7)) * 8;
    a_src[i] = xbf + (size_t)gr * KP + a_sl[i];
    a_dst[i] = (ushort*)&As[0][(w * 2 + i) * 512];
  }
  int b_sl[4]; const ushort* b_src[4]; ushort* b_dst[4];
#pragma unroll
  for (int j = 0; j < 4; ++j) {
    int r = (w * 4 + j) * 8 + lr;                 // 0..127
    b_sl[j] = (lt ^ (r & 7)) * 8;
    b_src[j] = Wt + (size_t)r * KP + b_sl[j];
    b_dst[j] = (ushort*)&Bs[0][(w * 4 + j) * 512];
  }
  const size_t bufstride_a = 64 * 64;   // ushorts
  const size_t bufstride_b = 128 * 64;

#define STAGE(buf, k0)                                                        \
  do {                                                                        \
    _Pragma("unroll")                                                         \
    for (int i = 0; i < 2; ++i)                                               \
      gload_lds16(a_src[i] + (k0), a_dst[i] + (size_t)(buf) * bufstride_a);   \
    _Pragma("unroll")                                                         \
    for (int j = 0; j < 4; ++j)                                               \
      gload_lds16(b_src[j] + (k0), b_dst[j] + (size_t)(buf) * bufstride_b);   \
  } while (0)

  int cur = 0;
  STAGE(0, 0);
  __syncthreads();

  for (int kt = 0; kt < NKT; ++kt) {
    if (kt + 1 < NKT) STAGE(cur ^ 1, (kt + 1) * 64);
#pragma unroll
    for (int kk = 0; kk < 2; ++kk) {
      bf16x8 a[2], b[4];
      const int sbase = kk * 4 + (lane >> 4);     // logical slot 0..7
#pragma unroll
      for (int m = 0; m < 2; ++m) {
        int r = wr * 32 + m * 16 + (lane & 15);
        int s = sbase ^ (r & 7);
        a[m] = *(const bf16x8*)&As[cur][r * 64 + s * 8];
      }
#pragma unroll
      for (int n = 0; n < 4; ++n) {
        int r = wc * 64 + n * 16 + (lane & 15);
        int s = sbase ^ (r & 7);
        b[n] = *(const bf16x8*)&Bs[cur][r * 64 + s * 8];
      }
#pragma unroll
      for (int m = 0; m < 2; ++m)
#pragma unroll
        for (int n = 0; n < 4; ++n)
          acc[m][n] = __builtin_amdgcn_mfma_f32_16x16x32_bf16(a[m], b[n], acc[m][n], 0, 0, 0);
    }
    __syncthreads();
    cur ^= 1;
  }
#undef STAGE

  // epilogue: D frag (m,n): row = (lane>>4)*4 + reg, col = lane&15
#pragma unroll
  for (int m = 0; m < 2; ++m) {
    int rbase = row0 + wr * 32 + m * 16 + (lane >> 4) * 4;
#pragma unroll
    for (int n = 0; n < 4; ++n) {
      int col = wc * 64 + n * 16 + (lane & 15);
#pragma unroll
      for (int r = 0; r < 4; ++r) {
        int grow = rbase + r;
        if (grow < N_NODES) h1pre[(size_t)grow * 128 + col] = acc[m][n][r];
      }
    }
  }
}

// ---------------- fallback GEMM1 (fp32 read, round-2 path) ----------------
__global__ __launch_bounds__(256) void k_gemm1_fp32(const float* __restrict__ x,
                                                    const ushort* __restrict__ Wt,
                                                    float* __restrict__ h1pre) {
  __shared__ ushort As[64 * 64];
  __shared__ ushort Bs[128 * 64];
  const int t    = threadIdx.x;
  const int lane = t & 63;
  const int wid  = t >> 6;
  const int wr   = wid >> 1;
  const int wc   = wid & 1;
  const int row0 = blockIdx.x * 64;
  f32x4 acc[2][4] = {};

  for (int k0 = 0; k0 < KP; k0 += 64) {
#pragma unroll
    for (int i = 0; i < 16; ++i) {
      int idx = t + 256 * i;
      int r = idx >> 6, k = idx & 63;
      int gr = row0 + r, gk = k0 + k;
      float v = 0.f;
      if (gr < N_NODES && gk < F_IN) v = x[(size_t)gr * F_IN + gk];
      int byte = (r * 128 + k * 2) ^ ((r & 7) << 4);
      *(ushort*)((char*)As + byte) = f2bf(v);
    }
#pragma unroll
    for (int p = 0; p < 4; ++p) {
      int r  = p * 32 + (t >> 3);
      int k8 = (t & 7) * 8;
      uint4 v = *(const uint4*)(&Wt[(size_t)r * KP + k0 + k8]);
      int byte = (r * 128 + k8 * 2) ^ ((r & 7) << 4);
      *(uint4*)((char*)Bs + byte) = v;
    }
    __syncthreads();
#pragma unroll
    for (int kk = 0; kk < 2; ++kk) {
      bf16x8 a[2], b[4];
      const int kbyte = (kk * 32 + (lane >> 4) * 8) * 2;
#pragma unroll
      for (int m = 0; m < 2; ++m) {
        int r = wr * 32 + m * 16 + (lane & 15);
        int byte = (r * 128 + kbyte) ^ ((r & 7) << 4);
        a[m] = *(const bf16x8*)((const char*)As + byte);
      }
#pragma unroll
      for (int n = 0; n < 4; ++n) {
        int r = wc * 64 + n * 16 + (lane & 15);
        int byte = (r * 128 + kbyte) ^ ((r & 7) << 4);
        b[n] = *(const bf16x8*)((const char*)Bs + byte);
      }
#pragma unroll
      for (int m = 0; m < 2; ++m)
#pragma unroll
        for (int n = 0; n < 4; ++n)
          acc[m][n] = __builtin_amdgcn_mfma_f32_16x16x32_bf16(a[m], b[n], acc[m][n], 0, 0, 0);
    }
    __syncthreads();
  }
#pragma unroll
  for (int m = 0; m < 2; ++m) {
    int rbase = row0 + wr * 32 + m * 16 + (lane >> 4) * 4;
#pragma unroll
    for (int n = 0; n < 4; ++n) {
      int col = wc * 64 + n * 16 + (lane & 15);
#pragma unroll
      for (int r = 0; r < 4; ++r) {
        int grow = rbase + r;
        if (grow < N_NODES) h1pre[(size_t)grow * 128 + col] = acc[m][n][r];
      }
    }
  }
}

// ---------------- CSR build ----------------
__global__ void k_hist(const int* __restrict__ ei, int* __restrict__ deg) {
  int e = blockIdx.x * blockDim.x + threadIdx.x;
  if (e < N_EDGES) atomicAdd(&deg[ei[N_EDGES + e]], 1);
}

__global__ __launch_bounds__(256) void k_scan_a(const int* __restrict__ deg,
                                                int* __restrict__ off,
                                                int* __restrict__ blksum) {
  __shared__ int sd[256];
  const int t = threadIdx.x;
  const int base = blockIdx.x * 2048 + t * 8;
  int v[8];
  int s = 0;
#pragma unroll
  for (int j = 0; j < 8; ++j) {
    int i = base + j;
    v[j] = (i < N_NODES) ? deg[i] : 0;
    s += v[j];
  }
  sd[t] = s;
  __syncthreads();
  for (int o = 1; o < 256; o <<= 1) {
    int u = (t >= o) ? sd[t - o] : 0;
    __syncthreads();
    sd[t] += u;
    __syncthreads();
  }
  int excl = sd[t] - s;
#pragma unroll
  for (int j = 0; j < 8; ++j) {
    int i = base + j;
    if (i < N_NODES) off[i] = excl;
    excl += v[j];
  }
  if (t == 255) blksum[blockIdx.x] = sd[255];
}

__global__ void k_scan_b(const int* __restrict__ blksum, int* __restrict__ blkoff) {
  if (threadIdx.x == 0) {
    int run = 0;
    for (int i = 0; i < 25; ++i) { blkoff[i] = run; run += blksum[i]; }
  }
}

__global__ void k_scan_c(int* __restrict__ off, int* __restrict__ cur,
                         const int* __restrict__ blkoff) {
  int i = blockIdx.x * blockDim.x + threadIdx.x;
  if (i < N_NODES) {
    int v = off[i] + blkoff[i >> 11];
    off[i] = v;
    cur[i] = v;
  }
}

__global__ void k_fill(const int* __restrict__ ei, int* __restrict__ cur,
                       int* __restrict__ esrc) {
  int e = blockIdx.x * blockDim.x + threadIdx.x;
  if (e < N_EDGES) {
    int s = ei[e];
    int d = ei[N_EDGES + e];
    int slot = atomicAdd(&cur[d], 1);
    esrc[slot] = s;
  }
}

// ---------------- aggregate layer 1: one wave (64 lanes = 64 feats) per dst ----------------
__global__ __launch_bounds__(256) void k_agg1(const float* __restrict__ h1pre,
                                              const int* __restrict__ off,
                                              const int* __restrict__ deg,
                                              const int* __restrict__ esrc,
                                              const float* __restrict__ b1,
                                              float* __restrict__ h1) {
  const int lane = threadIdx.x & 63;
  const int d = blockIdx.x * 4 + (threadIdx.x >> 6);
  if (d >= N_NODES) return;
  const int dg = deg[d];
  const int base = off[d];
  float acc = 0.f;
  for (int j = 0; j < dg; ++j) {
    int s = esrc[base + j];
    acc += h1pre[(size_t)s * 128 + lane];
  }
  const float inv = (dg > 0) ? 1.f / (float)dg : 0.f;
  h1[(size_t)d * 64 + lane] = acc * inv + b1[lane] + h1pre[(size_t)d * 128 + 64 + lane];
}

// ---------------- GEMM2: h1[50000,64] @ [W2_l|W2_r][64,64] -> m2[50000,64] ----------------
__global__ __launch_bounds__(256) void k_gemm2(const float* __restrict__ h1,
                                               const float* __restrict__ W2l,
                                               const float* __restrict__ W2r,
                                               float* __restrict__ m2) {
  __shared__ __align__(16) float Ws[64][68];
  __shared__ __align__(16) float Hs[32][68];
  const int t = threadIdx.x;
#pragma unroll
  for (int i = 0; i < 16; ++i) {
    int idx = t + 256 * i;
    int k = idx >> 6, c = idx & 63;
    Ws[k][c] = (c < 32) ? W2l[k * 32 + c] : W2r[k * 32 + (c - 32)];
  }
  const int r0 = blockIdx.x * 32;
#pragma unroll
  for (int i = 0; i < 8; ++i) {
    int idx = t + 256 * i;
    int r = idx >> 6, c = idx & 63;
    int gr = r0 + r;
    Hs[r][c] = (gr < N_NODES) ? h1[(size_t)gr * 64 + c] : 0.f;
  }
  __syncthreads();
  const int rl = t >> 3;
  const int c0 = (t & 7) * 8;
  float acc[8] = {};
#pragma unroll 8
  for (int k = 0; k < 64; ++k) {
    float hv = Hs[rl][k];
#pragma unroll
    for (int j = 0; j < 8; ++j) acc[j] = fmaf(hv, Ws[k][c0 + j], acc[j]);
  }
  const int gr = r0 + rl;
  if (gr < N_NODES) {
    *(float4*)(&m2[(size_t)gr * 64 + c0])     = make_float4(acc[0], acc[1], acc[2], acc[3]);
    *(float4*)(&m2[(size_t)gr * 64 + c0 + 4]) = make_float4(acc[4], acc[5], acc[6], acc[7]);
  }
}

// ---------------- aggregate layer 2 + relu + log_softmax ----------------
__global__ __launch_bounds__(256) void k_agg2(const float* __restrict__ m2,
                                              const int* __restrict__ off,
                                              const int* __restrict__ deg,
                                              const int* __restrict__ esrc,
                                              const float* __restrict__ b2,
                                              float* __restrict__ out) {
  const int lane = threadIdx.x & 63;
  const int half = lane >> 5;
  const int f = lane & 31;
  const int d = blockIdx.x * 8 + ((threadIdx.x >> 6) << 1) + half;  // 50000 % 8 == 0
  const int dg = deg[d];
  const int base = off[d];
  float acc = 0.f;
  for (int j = 0; j < dg; ++j) {
    int s = esrc[base + j];
    acc += m2[(size_t)s * 64 + f];
  }
  const float inv = (dg > 0) ? 1.f / (float)dg : 0.f;
  float v = acc * inv + b2[f] + m2[(size_t)d * 64 + 32 + f];
  v = fmaxf(v, 0.f);
  float m = v;
#pragma unroll
  for (int o = 16; o > 0; o >>= 1) m = fmaxf(m, __shfl_xor(m, o, 32));
  float e = expf(v - m);
  float sum = e;
#pragma unroll
  for (int o = 16; o > 0; o >>= 1) sum += __shfl_xor(sum, o, 32);
  out[(size_t)d * 32 + f] = v - m - logf(sum);
}

extern "C" void kernel_launch(void* const* d_in, const int* in_sizes, int n_in,
                              void* d_out, int out_size, void* d_ws, size_t ws_size,
                              hipStream_t stream) {
  const float* x   = (const float*)d_in[0];
  const int*   ei  = (const int*)d_in[1];
  const float* W1l = (const float*)d_in[2];
  const float* b1  = (const float*)d_in[3];
  const float* W1r = (const float*)d_in[4];
  const float* W2l = (const float*)d_in[5];
  const float* b2  = (const float*)d_in[6];
  const float* W2r = (const float*)d_in[7];
  float* out = (float*)d_out;

  char* ws = (char*)d_ws;
  float*  h1pre = (float*)(ws + OFF_H1PRE);
  float*  h1    = (float*)(ws + OFF_H1);
  float*  m2    = (float*)(ws + OFF_M2);
  int*    deg   = (int*)(ws + OFF_DEG);
  int*    off   = (int*)(ws + OFF_OFFS);
  int*    cur   = (int*)(ws + OFF_CUR);
  int*    esrc  = (int*)(ws + OFF_ESRC);
  int*    bsum  = (int*)(ws + OFF_BSUM);
  int*    boff  = (int*)(ws + OFF_BOFF);
  ushort* Wt    = (ushort*)(ws + OFF_WT);
  ushort* xbf   = (ushort*)(ws + OFF_XBF);

  const bool big = ws_size >= OFF_XBF + XBF_BYTES;

  k_zero_deg<<<(N_NODES + 255) / 256, 256, 0, stream>>>(deg);

  {
    dim3 g(128, (KP + 255) / 256);
    k_prep_w<<<g, 256, 0, stream>>>(W1l, W1r, Wt);
  }
  if (big) {
    k_cvt<<<N_NODES, 256, 0, stream>>>(x, xbf);
    k_gemm1_bf<<<(N_NODES + 63) / 64, 256, 0, stream>>>(xbf, Wt, h1pre);
  } else {
    k_gemm1_fp32<<<(N_NODES + 63) / 64, 256, 0, stream>>>(x, Wt, h1pre);
  }

  k_hist<<<(N_EDGES + 255) / 256, 256, 0, stream>>>(ei, deg);
  k_scan_a<<<25, 256, 0, stream>>>(deg, off, bsum);
  k_scan_b<<<1, 64, 0, stream>>>(bsum, boff);
  k_scan_c<<<(N_NODES + 255) / 256, 256, 0, stream>>>(off, cur, boff);
  k_fill<<<(N_EDGES + 255) / 256, 256, 0, stream>>>(ei, cur, esrc);

  k_agg1<<<N_NODES / 4, 256, 0, stream>>>(h1pre, off, deg, esrc, b1, h1);
  k_gemm2<<<(N_NODES + 31) / 32, 256, 0, stream>>>(h1, W2l, W2r, m2);
  k_agg2<<<N_NODES / 8, 256, 0, stream>>>(m2, off, deg, esrc, b2, out);
}

// Round 5
// 302.327 us; speedup vs baseline: 2.8905x; 1.2925x over previous
//
#include <hip/hip_runtime.h>
#include <hip/hip_bf16.h>
#include <cstdint>
#include <cstddef>

// GraphSAGE 2-layer: h1 = mean_agg(x@W1_l) + b1 + x@W1_r ; h2 = mean_agg(h1@W2_l) + b2 + h1@W2_r
// out = log_softmax(relu(h2))
//
// Round 5: (1) kill the x->bf16 cvt pass; gemm1 reads fp32 x directly with
// reg-staged A (dwordx4 + in-reg cvt + swizzled ds_write_b128), B via
// global_load_lds. Saves ~294 MB of HBM traffic vs cvt+reread.
// (2) agg1/agg2: 4-way unrolled independent accumulators (4 loads in flight).
// Learned: fillBufferAligned rows in top-5 are harness poison (untimed).

#define N_NODES 50000
#define N_EDGES 800000
#define F_IN    1433
#define KP      1472   // 23 * 64, zero-padded K
#define NKT     23     // K tiles of 64

typedef __attribute__((ext_vector_type(8))) short bf16x8;
typedef __attribute__((ext_vector_type(4))) float f32x4;

// ---- workspace layout (bytes) ----
static constexpr size_t OFF_H1PRE = 0;                               // 50000*128*4 = 25,600,000
static constexpr size_t OFF_H1    = OFF_H1PRE + 25600000;            // 50000*64*4  = 12,800,000
static constexpr size_t OFF_M2    = OFF_H1    + 12800000;            // 50000*64*4  = 12,800,000
static constexpr size_t OFF_DEG   = OFF_M2    + 12800000;            // 50000*4
static constexpr size_t OFF_OFFS  = OFF_DEG   + 200000;              // 50000*4
static constexpr size_t OFF_CUR   = OFF_OFFS  + 200000;              // 50000*4
static constexpr size_t OFF_ESRC  = OFF_CUR   + 200000;              // 800000*4
static constexpr size_t OFF_BSUM  = OFF_ESRC  + 3200000;             // 25*4 (pad 256)
static constexpr size_t OFF_BOFF  = OFF_BSUM  + 256;                 // 25*4 (pad 256)
static constexpr size_t OFF_WT    = OFF_BOFF  + 256;                 // 128*1472*2 = 376,832

__device__ inline ushort f2bf(float f) {
  union { float f; uint32_t u; } v; v.f = f;
  uint32_t u = v.u + 0x7FFFu + ((v.u >> 16) & 1u);   // RNE
  return (ushort)(u >> 16);
}

__device__ __forceinline__ void gload_lds16(const void* g, void* l) {
  __builtin_amdgcn_global_load_lds(
      (const __attribute__((address_space(1))) void*)g,
      (__attribute__((address_space(3))) void*)l, 16, 0, 0);
}

// ---- zero deg ----
__global__ __launch_bounds__(256) void k_zero_deg(int* __restrict__ deg) {
  int i = blockIdx.x * 256 + threadIdx.x;
  if (i < N_NODES) deg[i] = 0;
}

// ---- weight prep: Wt[c][k] = c<64 ? W1l[k][c] : W1r[k][c-64], bf16, k-padded ----
__global__ __launch_bounds__(256) void k_prep_w(const float* __restrict__ Wl,
                                                const float* __restrict__ Wr,
                                                ushort* __restrict__ Wt) {
  const int c = blockIdx.x;                       // 0..127
  const int k = blockIdx.y * 256 + threadIdx.x;
  if (k >= KP) return;
  float v = 0.f;
  if (k < F_IN) v = (c < 64) ? Wl[k * 64 + c] : Wr[k * 64 + (c - 64)];
  Wt[(size_t)c * KP + k] = f2bf(v);
}

// ---------------- GEMM1: fp32 x read directly, reg-staged A, MFMA bf16 ----------------
// BM=64, BN=128, BK=64, double-buffered. LDS stores logical (row r, 16B slot s)
// at physical slot s^(r&7). A: global fp32 -> regs -> cvt -> swizzled ds_write.
// B: global_load_lds (linear dest, pre-swizzled source). K-tail needs no guard:
// Wt is zero-padded, so garbage A in k>=1433 contributes 0; loads clamp index.
__global__ __launch_bounds__(256) void k_gemm1f(const float* __restrict__ x,
                                                const ushort* __restrict__ Wt,
                                                float* __restrict__ h1pre) {
  __shared__ __align__(16) ushort As[2][64 * 64];    // 8 KB per buf
  __shared__ __align__(16) ushort Bs[2][128 * 64];   // 16 KB per buf
  const int t    = threadIdx.x;
  const int lane = t & 63;
  const int w    = t >> 6;             // 0..3
  const int wr   = w >> 1;
  const int wc   = w & 1;
  const int row0 = blockIdx.x * 64;

  // A staging mapping: thread t -> row ar (0..63), k-quarter aq (16 floats)
  const int ar = t >> 2;
  const int aq = t & 3;
  const size_t abase = (size_t)(row0 + ar) * F_IN + aq * 16;
  const size_t LIM   = (size_t)N_NODES * F_IN - 4;   // clamp: valid garbage, zero weights
  const int aoff  = ar * 64;                          // ushort offset of row
  const int asw0  = ((aq * 2)     ^ (ar & 7)) * 8;    // swizzled slot, ushorts
  const int asw1  = ((aq * 2 + 1) ^ (ar & 7)) * 8;

  // B staging per-wave invariants
  const int lr = lane >> 3, lt = lane & 7;
  const ushort* b_src[4];
  ushort* b_dst0[4];
#pragma unroll
  for (int j = 0; j < 4; ++j) {
    int r = (w * 4 + j) * 8 + lr;                 // 0..127
    b_src[j]  = Wt + (size_t)r * KP + (lt ^ (r & 7)) * 8;
    b_dst0[j] = (ushort*)&Bs[0][(w * 4 + j) * 512];
  }
  const size_t BUFB = 128 * 64;

  f32x4 acc[2][4] = {};
  f32x4 av[4];

#define LOADA(k0)                                                   \
  do {                                                              \
    _Pragma("unroll")                                               \
    for (int c = 0; c < 4; ++c) {                                   \
      size_t idx = abase + (size_t)(k0) + c * 4;                    \
      if (idx > LIM) idx = LIM;                                     \
      __builtin_memcpy(&av[c], x + idx, 16);                        \
    }                                                               \
  } while (0)

#define WRITEA(buf)                                                 \
  do {                                                              \
    bf16x8 w0, w1;                                                  \
    _Pragma("unroll")                                               \
    for (int c = 0; c < 2; ++c)                                     \
      _Pragma("unroll")                                             \
      for (int e = 0; e < 4; ++e) {                                 \
        w0[c * 4 + e] = (short)f2bf(av[c][e]);                      \
        w1[c * 4 + e] = (short)f2bf(av[c + 2][e]);                  \
      }                                                             \
    *(bf16x8*)&As[buf][aoff + asw0] = w0;                           \
    *(bf16x8*)&As[buf][aoff + asw1] = w1;                           \
  } while (0)

#define STAGEB(buf, k0)                                             \
  do {                                                              \
    _Pragma("unroll")                                               \
    for (int j = 0; j < 4; ++j)                                     \
      gload_lds16(b_src[j] + (k0), b_dst0[j] + (size_t)(buf) * BUFB); \
  } while (0)

  // prologue
  LOADA(0);
  STAGEB(0, 0);
  WRITEA(0);
  __syncthreads();

  int cur = 0;
  for (int kt = 0; kt < NKT; ++kt) {
    const int nxt = cur ^ 1;
    if (kt + 1 < NKT) {
      LOADA((kt + 1) * 64);          // issue early: lands during MFMA phase
      STAGEB(nxt, (kt + 1) * 64);
    }
#pragma unroll
    for (int kk = 0; kk < 2; ++kk) {
      bf16x8 a[2], b[4];
      const int sbase = kk * 4 + (lane >> 4);     // logical slot 0..7
#pragma unroll
      for (int m = 0; m < 2; ++m) {
        int r = wr * 32 + m * 16 + (lane & 15);
        int s = sbase ^ (r & 7);
        a[m] = *(const bf16x8*)&As[cur][r * 64 + s * 8];
      }
#pragma unroll
      for (int n = 0; n < 4; ++n) {
        int r = wc * 64 + n * 16 + (lane & 15);
        int s = sbase ^ (r & 7);
        b[n] = *(const bf16x8*)&Bs[cur][r * 64 + s * 8];
      }
#pragma unroll
      for (int m = 0; m < 2; ++m)
#pragma unroll
        for (int n = 0; n < 4; ++n)
          acc[m][n] = __builtin_amdgcn_mfma_f32_16x16x32_bf16(a[m], b[n], acc[m][n], 0, 0, 0);
    }
    if (kt + 1 < NKT) WRITEA(nxt);   // vmcnt-waits A loads, cvt, ds_write
    __syncthreads();
    cur = nxt;
  }
#undef LOADA
#undef WRITEA
#undef STAGEB

  // epilogue: D frag (m,n): row = (lane>>4)*4 + reg, col = lane&15
#pragma unroll
  for (int m = 0; m < 2; ++m) {
    int rbase = row0 + wr * 32 + m * 16 + (lane >> 4) * 4;
#pragma unroll
    for (int n = 0; n < 4; ++n) {
      int col = wc * 64 + n * 16 + (lane & 15);
#pragma unroll
      for (int r = 0; r < 4; ++r) {
        int grow = rbase + r;
        if (grow < N_NODES) h1pre[(size_t)grow * 128 + col] = acc[m][n][r];
      }
    }
  }
}

// ---------------- CSR build ----------------
__global__ void k_hist(const int* __restrict__ ei, int* __restrict__ deg) {
  int e = blockIdx.x * blockDim.x + threadIdx.x;
  if (e < N_EDGES) atomicAdd(&deg[ei[N_EDGES + e]], 1);
}

__global__ __launch_bounds__(256) void k_scan_a(const int* __restrict__ deg,
                                                int* __restrict__ off,
                                                int* __restrict__ blksum) {
  __shared__ int sd[256];
  const int t = threadIdx.x;
  const int base = blockIdx.x * 2048 + t * 8;
  int v[8];
  int s = 0;
#pragma unroll
  for (int j = 0; j < 8; ++j) {
    int i = base + j;
    v[j] = (i < N_NODES) ? deg[i] : 0;
    s += v[j];
  }
  sd[t] = s;
  __syncthreads();
  for (int o = 1; o < 256; o <<= 1) {
    int u = (t >= o) ? sd[t - o] : 0;
    __syncthreads();
    sd[t] += u;
    __syncthreads();
  }
  int excl = sd[t] - s;
#pragma unroll
  for (int j = 0; j < 8; ++j) {
    int i = base + j;
    if (i < N_NODES) off[i] = excl;
    excl += v[j];
  }
  if (t == 255) blksum[blockIdx.x] = sd[255];
}

__global__ void k_scan_b(const int* __restrict__ blksum, int* __restrict__ blkoff) {
  if (threadIdx.x == 0) {
    int run = 0;
    for (int i = 0; i < 25; ++i) { blkoff[i] = run; run += blksum[i]; }
  }
}

__global__ void k_scan_c(int* __restrict__ off, int* __restrict__ cur,
                         const int* __restrict__ blkoff) {
  int i = blockIdx.x * blockDim.x + threadIdx.x;
  if (i < N_NODES) {
    int v = off[i] + blkoff[i >> 11];
    off[i] = v;
    cur[i] = v;
  }
}

__global__ void k_fill(const int* __restrict__ ei, int* __restrict__ cur,
                       int* __restrict__ esrc) {
  int e = blockIdx.x * blockDim.x + threadIdx.x;
  if (e < N_EDGES) {
    int s = ei[e];
    int d = ei[N_EDGES + e];
    int slot = atomicAdd(&cur[d], 1);
    esrc[slot] = s;
  }
}

// ---------------- aggregate layer 1: one wave per dst, 4-way unrolled gather ----------------
__global__ __launch_bounds__(256) void k_agg1(const float* __restrict__ h1pre,
                                              const int* __restrict__ off,
                                              const int* __restrict__ deg,
                                              const int* __restrict__ esrc,
                                              const float* __restrict__ b1,
                                              float* __restrict__ h1) {
  const int lane = threadIdx.x & 63;
  const int d = blockIdx.x * 4 + (threadIdx.x >> 6);
  if (d >= N_NODES) return;
  const int dg = deg[d];
  const int base = off[d];
  float a0 = 0.f, a1 = 0.f, a2 = 0.f, a3 = 0.f;
  int j = 0;
  for (; j + 4 <= dg; j += 4) {
    int s0 = esrc[base + j], s1 = esrc[base + j + 1];
    int s2 = esrc[base + j + 2], s3 = esrc[base + j + 3];
    a0 += h1pre[(size_t)s0 * 128 + lane];
    a1 += h1pre[(size_t)s1 * 128 + lane];
    a2 += h1pre[(size_t)s2 * 128 + lane];
    a3 += h1pre[(size_t)s3 * 128 + lane];
  }
  for (; j < dg; ++j) a0 += h1pre[(size_t)esrc[base + j] * 128 + lane];
  float acc = (a0 + a1) + (a2 + a3);
  const float inv = (dg > 0) ? 1.f / (float)dg : 0.f;
  h1[(size_t)d * 64 + lane] = acc * inv + b1[lane] + h1pre[(size_t)d * 128 + 64 + lane];
}

// ---------------- GEMM2: h1[50000,64] @ [W2_l|W2_r][64,64] -> m2[50000,64] ----------------
__global__ __launch_bounds__(256) void k_gemm2(const float* __restrict__ h1,
                                               const float* __restrict__ W2l,
                                               const float* __restrict__ W2r,
                                               float* __restrict__ m2) {
  __shared__ __align__(16) float Ws[64][68];
  __shared__ __align__(16) float Hs[32][68];
  const int t = threadIdx.x;
#pragma unroll
  for (int i = 0; i < 16; ++i) {
    int idx = t + 256 * i;
    int k = idx >> 6, c = idx & 63;
    Ws[k][c] = (c < 32) ? W2l[k * 32 + c] : W2r[k * 32 + (c - 32)];
  }
  const int r0 = blockIdx.x * 32;
#pragma unroll
  for (int i = 0; i < 8; ++i) {
    int idx = t + 256 * i;
    int r = idx >> 6, c = idx & 63;
    int gr = r0 + r;
    Hs[r][c] = (gr < N_NODES) ? h1[(size_t)gr * 64 + c] : 0.f;
  }
  __syncthreads();
  const int rl = t >> 3;
  const int c0 = (t & 7) * 8;
  float acc[8] = {};
#pragma unroll 8
  for (int k = 0; k < 64; ++k) {
    float hv = Hs[rl][k];
#pragma unroll
    for (int j = 0; j < 8; ++j) acc[j] = fmaf(hv, Ws[k][c0 + j], acc[j]);
  }
  const int gr = r0 + rl;
  if (gr < N_NODES) {
    *(float4*)(&m2[(size_t)gr * 64 + c0])     = make_float4(acc[0], acc[1], acc[2], acc[3]);
    *(float4*)(&m2[(size_t)gr * 64 + c0 + 4]) = make_float4(acc[4], acc[5], acc[6], acc[7]);
  }
}

// ---------------- aggregate layer 2 + relu + log_softmax, 4-way unrolled ----------------
__global__ __launch_bounds__(256) void k_agg2(const float* __restrict__ m2,
                                              const int* __restrict__ off,
                                              const int* __restrict__ deg,
                                              const int* __restrict__ esrc,
                                              const float* __restrict__ b2,
                                              float* __restrict__ out) {
  const int lane = threadIdx.x & 63;
  const int half = lane >> 5;
  const int f = lane & 31;
  const int d = blockIdx.x * 8 + ((threadIdx.x >> 6) << 1) + half;  // 50000 % 8 == 0
  const int dg = deg[d];
  const int base = off[d];
  float a0 = 0.f, a1 = 0.f, a2 = 0.f, a3 = 0.f;
  int j = 0;
  for (; j + 4 <= dg; j += 4) {
    int s0 = esrc[base + j], s1 = esrc[base + j + 1];
    int s2 = esrc[base + j + 2], s3 = esrc[base + j + 3];
    a0 += m2[(size_t)s0 * 64 + f];
    a1 += m2[(size_t)s1 * 64 + f];
    a2 += m2[(size_t)s2 * 64 + f];
    a3 += m2[(size_t)s3 * 64 + f];
  }
  for (; j < dg; ++j) a0 += m2[(size_t)esrc[base + j] * 64 + f];
  float acc = (a0 + a1) + (a2 + a3);
  const float inv = (dg > 0) ? 1.f / (float)dg : 0.f;
  float v = acc * inv + b2[f] + m2[(size_t)d * 64 + 32 + f];
  v = fmaxf(v, 0.f);
  float m = v;
#pragma unroll
  for (int o = 16; o > 0; o >>= 1) m = fmaxf(m, __shfl_xor(m, o, 32));
  float e = expf(v - m);
  float sum = e;
#pragma unroll
  for (int o = 16; o > 0; o >>= 1) sum += __shfl_xor(sum, o, 32);
  out[(size_t)d * 32 + f] = v - m - logf(sum);
}

extern "C" void kernel_launch(void* const* d_in, const int* in_sizes, int n_in,
                              void* d_out, int out_size, void* d_ws, size_t ws_size,
                              hipStream_t stream) {
  const float* x   = (const float*)d_in[0];
  const int*   ei  = (const int*)d_in[1];
  const float* W1l = (const float*)d_in[2];
  const float* b1  = (const float*)d_in[3];
  const float* W1r = (const float*)d_in[4];
  const float* W2l = (const float*)d_in[5];
  const float* b2  = (const float*)d_in[6];
  const float* W2r = (const float*)d_in[7];
  float* out = (float*)d_out;

  char* ws = (char*)d_ws;
  float*  h1pre = (float*)(ws + OFF_H1PRE);
  float*  h1    = (float*)(ws + OFF_H1);
  float*  m2    = (float*)(ws + OFF_M2);
  int*    deg   = (int*)(ws + OFF_DEG);
  int*    off   = (int*)(ws + OFF_OFFS);
  int*    cur   = (int*)(ws + OFF_CUR);
  int*    esrc  = (int*)(ws + OFF_ESRC);
  int*    bsum  = (int*)(ws + OFF_BSUM);
  int*    boff  = (int*)(ws + OFF_BOFF);
  ushort* Wt    = (ushort*)(ws + OFF_WT);

  k_zero_deg<<<(N_NODES + 255) / 256, 256, 0, stream>>>(deg);

  {
    dim3 g(128, (KP + 255) / 256);
    k_prep_w<<<g, 256, 0, stream>>>(W1l, W1r, Wt);
  }
  k_gemm1f<<<(N_NODES + 63) / 64, 256, 0, stream>>>(x, Wt, h1pre);

  k_hist<<<(N_EDGES + 255) / 256, 256, 0, stream>>>(ei, deg);
  k_scan_a<<<25, 256, 0, stream>>>(deg, off, bsum);
  k_scan_b<<<1, 64, 0, stream>>>(bsum, boff);
  k_scan_c<<<(N_NODES + 255) / 256, 256, 0, stream>>>(off, cur, boff);
  k_fill<<<(N_EDGES + 255) / 256, 256, 0, stream>>>(ei, cur, esrc);

  k_agg1<<<N_NODES / 4, 256, 0, stream>>>(h1pre, off, deg, esrc, b1, h1);
  k_gemm2<<<(N_NODES + 31) / 32, 256, 0, stream>>>(h1, W2l, W2r, m2);
  k_agg2<<<N_NODES / 8, 256, 0, stream>>>(m2, off, deg, esrc, b2, out);
}

// Round 6
// 294.713 us; speedup vs baseline: 2.9651x; 1.0258x over previous
//
#include <hip/hip_runtime.h>
#include <hip/hip_bf16.h>
#include <cstdint>
#include <cstddef>

// GraphSAGE 2-layer: h1 = mean_agg(x@W1_l) + b1 + x@W1_r ; h2 = mean_agg(h1@W2_l) + b2 + h1@W2_r
// out = log_softmax(relu(h2))
//
// Round 6: (1) gemm1f BM 64->32 (LDS 40KB, 4 blocks/CU, 1563 blocks: 2x the
// inter-block latency overlap; A HBM traffic unchanged). (2) k_scan_b (single
// thread, ~50 dependent global accesses) fused into k_scan_c (per-block
// 25-element wave-reduce prefix). (3) agg1/agg2 8-way unrolled gathers.

#define N_NODES 50000
#define N_EDGES 800000
#define F_IN    1433
#define KP      1472   // 23 * 64, zero-padded K
#define NKT     23     // K tiles of 64

typedef __attribute__((ext_vector_type(8))) short bf16x8;
typedef __attribute__((ext_vector_type(4))) float f32x4;

// ---- workspace layout (bytes) ----
static constexpr size_t OFF_H1PRE = 0;                               // 50000*128*4 = 25,600,000
static constexpr size_t OFF_H1    = OFF_H1PRE + 25600000;            // 50000*64*4  = 12,800,000
static constexpr size_t OFF_M2    = OFF_H1    + 12800000;            // 50000*64*4  = 12,800,000
static constexpr size_t OFF_DEG   = OFF_M2    + 12800000;            // 50000*4
static constexpr size_t OFF_OFFS  = OFF_DEG   + 200000;              // 50000*4
static constexpr size_t OFF_CUR   = OFF_OFFS  + 200000;              // 50000*4
static constexpr size_t OFF_ESRC  = OFF_CUR   + 200000;              // 800000*4
static constexpr size_t OFF_BSUM  = OFF_ESRC  + 3200000;             // 25*4 (pad 256)
static constexpr size_t OFF_BOFF  = OFF_BSUM  + 256;                 // 25*4 (pad 256)
static constexpr size_t OFF_WT    = OFF_BOFF  + 256;                 // 128*1472*2 = 376,832

__device__ inline ushort f2bf(float f) {
  union { float f; uint32_t u; } v; v.f = f;
  uint32_t u = v.u + 0x7FFFu + ((v.u >> 16) & 1u);   // RNE
  return (ushort)(u >> 16);
}

__device__ __forceinline__ void gload_lds16(const void* g, void* l) {
  __builtin_amdgcn_global_load_lds(
      (const __attribute__((address_space(1))) void*)g,
      (__attribute__((address_space(3))) void*)l, 16, 0, 0);
}

// ---- zero deg ----
__global__ __launch_bounds__(256) void k_zero_deg(int* __restrict__ deg) {
  int i = blockIdx.x * 256 + threadIdx.x;
  if (i < N_NODES) deg[i] = 0;
}

// ---- weight prep: Wt[c][k] = c<64 ? W1l[k][c] : W1r[k][c-64], bf16, k-padded ----
__global__ __launch_bounds__(256) void k_prep_w(const float* __restrict__ Wl,
                                                const float* __restrict__ Wr,
                                                ushort* __restrict__ Wt) {
  const int c = blockIdx.x;                       // 0..127
  const int k = blockIdx.y * 256 + threadIdx.x;
  if (k >= KP) return;
  float v = 0.f;
  if (k < F_IN) v = (c < 64) ? Wl[k * 64 + c] : Wr[k * 64 + (c - 64)];
  Wt[(size_t)c * KP + k] = f2bf(v);
}

// ---------------- GEMM1: fp32 x read directly, reg-staged A, MFMA bf16 ----------------
// BM=32, BN=128, BK=64, double-buffered. LDS stores logical (row r, 16B slot s)
// at physical slot s^(r&7). A: global fp32 -> regs -> cvt -> swizzled ds_write.
// B: global_load_lds (linear dest, pre-swizzled source). Zero-padded Wt makes
// the K-tail self-masking; A loads clamp the flat index (garbage x zero = 0).
__global__ __launch_bounds__(256) void k_gemm1f(const float* __restrict__ x,
                                                const ushort* __restrict__ Wt,
                                                float* __restrict__ h1pre) {
  __shared__ __align__(16) ushort As[2][32 * 64];    // 4 KB per buf
  __shared__ __align__(16) ushort Bs[2][128 * 64];   // 16 KB per buf
  const int t    = threadIdx.x;
  const int lane = t & 63;
  const int w    = t >> 6;             // 0..3
  const int wr   = w >> 1;             // row band (16 rows)
  const int wc   = w & 1;              // col band (64 cols)
  const int row0 = blockIdx.x * 32;

  // A staging: thread t -> row ar (0..31, 8 threads/row), 8-float chunk aq (0..7)
  const int ar = t >> 3;
  const int aq = t & 7;
  const size_t abase = (size_t)(row0 + ar) * F_IN + aq * 8;
  const size_t LIM   = (size_t)N_NODES * F_IN - 4;   // clamp: valid garbage, zero weights
  const int aoff = ar * 64;                          // ushort offset of row
  const int asw  = (aq ^ (ar & 7)) * 8;              // swizzled slot, ushorts

  // B staging per-wave invariants
  const int lr = lane >> 3, lt = lane & 7;
  const ushort* b_src[4];
  ushort* b_dst0[4];
#pragma unroll
  for (int j = 0; j < 4; ++j) {
    int r = (w * 4 + j) * 8 + lr;                 // 0..127
    b_src[j]  = Wt + (size_t)r * KP + (lt ^ (r & 7)) * 8;
    b_dst0[j] = (ushort*)&Bs[0][(w * 4 + j) * 512];
  }
  const size_t BUFB = 128 * 64;

  f32x4 acc[4] = {};
  f32x4 av[2];

#define LOADA(k0)                                                   \
  do {                                                              \
    _Pragma("unroll")                                               \
    for (int c = 0; c < 2; ++c) {                                   \
      size_t idx = abase + (size_t)(k0) + c * 4;                    \
      if (idx > LIM) idx = LIM;                                     \
      __builtin_memcpy(&av[c], x + idx, 16);                        \
    }                                                               \
  } while (0)

#define WRITEA(buf)                                                 \
  do {                                                              \
    bf16x8 w0;                                                      \
    _Pragma("unroll")                                               \
    for (int e = 0; e < 4; ++e) {                                   \
      w0[e]     = (short)f2bf(av[0][e]);                            \
      w0[4 + e] = (short)f2bf(av[1][e]);                            \
    }                                                               \
    *(bf16x8*)&As[buf][aoff + asw] = w0;                            \
  } while (0)

#define STAGEB(buf, k0)                                             \
  do {                                                              \
    _Pragma("unroll")                                               \
    for (int j = 0; j < 4; ++j)                                     \
      gload_lds16(b_src[j] + (k0), b_dst0[j] + (size_t)(buf) * BUFB); \
  } while (0)

  // prologue
  LOADA(0);
  STAGEB(0, 0);
  WRITEA(0);
  __syncthreads();

  int cur = 0;
  for (int kt = 0; kt < NKT; ++kt) {
    const int nxt = cur ^ 1;
    if (kt + 1 < NKT) {
      LOADA((kt + 1) * 64);          // issue early: lands during MFMA phase
      STAGEB(nxt, (kt + 1) * 64);
    }
#pragma unroll
    for (int kk = 0; kk < 2; ++kk) {
      bf16x8 a, b[4];
      const int sbase = kk * 4 + (lane >> 4);     // logical slot 0..7
      {
        int r = wr * 16 + (lane & 15);
        int s = sbase ^ (r & 7);
        a = *(const bf16x8*)&As[cur][r * 64 + s * 8];
      }
#pragma unroll
      for (int n = 0; n < 4; ++n) {
        int r = wc * 64 + n * 16 + (lane & 15);
        int s = sbase ^ (r & 7);
        b[n] = *(const bf16x8*)&Bs[cur][r * 64 + s * 8];
      }
#pragma unroll
      for (int n = 0; n < 4; ++n)
        acc[n] = __builtin_amdgcn_mfma_f32_16x16x32_bf16(a, b[n], acc[n], 0, 0, 0);
    }
    if (kt + 1 < NKT) WRITEA(nxt);   // vmcnt-waits A loads, cvt, ds_write
    __syncthreads();
    cur = nxt;
  }
#undef LOADA
#undef WRITEA
#undef STAGEB

  // epilogue: D frag n: row = (lane>>4)*4 + reg, col = lane&15
  {
    int rbase = row0 + wr * 16 + (lane >> 4) * 4;
#pragma unroll
    for (int n = 0; n < 4; ++n) {
      int col = wc * 64 + n * 16 + (lane & 15);
#pragma unroll
      for (int r = 0; r < 4; ++r) {
        int grow = rbase + r;
        if (grow < N_NODES) h1pre[(size_t)grow * 128 + col] = acc[n][r];
      }
    }
  }
}

// ---------------- CSR build ----------------
__global__ void k_hist(const int* __restrict__ ei, int* __restrict__ deg) {
  int e = blockIdx.x * blockDim.x + threadIdx.x;
  if (e < N_EDGES) atomicAdd(&deg[ei[N_EDGES + e]], 1);
}

__global__ __launch_bounds__(256) void k_scan_a(const int* __restrict__ deg,
                                                int* __restrict__ off,
                                                int* __restrict__ blksum) {
  __shared__ int sd[256];
  const int t = threadIdx.x;
  const int base = blockIdx.x * 2048 + t * 8;
  int v[8];
  int s = 0;
#pragma unroll
  for (int j = 0; j < 8; ++j) {
    int i = base + j;
    v[j] = (i < N_NODES) ? deg[i] : 0;
    s += v[j];
  }
  sd[t] = s;
  __syncthreads();
  for (int o = 1; o < 256; o <<= 1) {
    int u = (t >= o) ? sd[t - o] : 0;
    __syncthreads();
    sd[t] += u;
    __syncthreads();
  }
  int excl = sd[t] - s;
#pragma unroll
  for (int j = 0; j < 8; ++j) {
    int i = base + j;
    if (i < N_NODES) off[i] = excl;
    excl += v[j];
  }
  if (t == 255) blksum[blockIdx.x] = sd[255];
}

// scan_c with fused chunk-offset computation (replaces single-thread scan_b):
// each 256-thread block lies within one 2048-chunk; wave 0 computes the
// prefix sum of blksum[0..c-1] (c = chunk index <= 24) via shfl reduce.
__global__ __launch_bounds__(256) void k_scan_c(int* __restrict__ off, int* __restrict__ cur,
                                                const int* __restrict__ blksum) {
  __shared__ int boffs;
  const int c = blockIdx.x >> 3;            // 2048/256
  if (threadIdx.x < 64) {
    int v = ((int)threadIdx.x < c) ? blksum[threadIdx.x] : 0;
#pragma unroll
    for (int o = 32; o > 0; o >>= 1) v += __shfl_xor(v, o);
    if (threadIdx.x == 0) boffs = v;
  }
  __syncthreads();
  int i = blockIdx.x * 256 + threadIdx.x;
  if (i < N_NODES) {
    int v = off[i] + boffs;
    off[i] = v;
    cur[i] = v;
  }
}

__global__ void k_fill(const int* __restrict__ ei, int* __restrict__ cur,
                       int* __restrict__ esrc) {
  int e = blockIdx.x * blockDim.x + threadIdx.x;
  if (e < N_EDGES) {
    int s = ei[e];
    int d = ei[N_EDGES + e];
    int slot = atomicAdd(&cur[d], 1);
    esrc[slot] = s;
  }
}

// ---------------- aggregate layer 1: one wave per dst, 8-way unrolled gather ----------------
__global__ __launch_bounds__(256) void k_agg1(const float* __restrict__ h1pre,
                                              const int* __restrict__ off,
                                              const int* __restrict__ deg,
                                              const int* __restrict__ esrc,
                                              const float* __restrict__ b1,
                                              float* __restrict__ h1) {
  const int lane = threadIdx.x & 63;
  const int d = blockIdx.x * 4 + (threadIdx.x >> 6);
  if (d >= N_NODES) return;
  const int dg = deg[d];
  const int base = off[d];
  float a0 = 0.f, a1 = 0.f, a2 = 0.f, a3 = 0.f;
  float a4 = 0.f, a5 = 0.f, a6 = 0.f, a7 = 0.f;
  int j = 0;
  for (; j + 8 <= dg; j += 8) {
    int s0 = esrc[base + j],     s1 = esrc[base + j + 1];
    int s2 = esrc[base + j + 2], s3 = esrc[base + j + 3];
    int s4 = esrc[base + j + 4], s5 = esrc[base + j + 5];
    int s6 = esrc[base + j + 6], s7 = esrc[base + j + 7];
    a0 += h1pre[(size_t)s0 * 128 + lane];
    a1 += h1pre[(size_t)s1 * 128 + lane];
    a2 += h1pre[(size_t)s2 * 128 + lane];
    a3 += h1pre[(size_t)s3 * 128 + lane];
    a4 += h1pre[(size_t)s4 * 128 + lane];
    a5 += h1pre[(size_t)s5 * 128 + lane];
    a6 += h1pre[(size_t)s6 * 128 + lane];
    a7 += h1pre[(size_t)s7 * 128 + lane];
  }
  for (; j + 4 <= dg; j += 4) {
    int s0 = esrc[base + j],     s1 = esrc[base + j + 1];
    int s2 = esrc[base + j + 2], s3 = esrc[base + j + 3];
    a0 += h1pre[(size_t)s0 * 128 + lane];
    a1 += h1pre[(size_t)s1 * 128 + lane];
    a2 += h1pre[(size_t)s2 * 128 + lane];
    a3 += h1pre[(size_t)s3 * 128 + lane];
  }
  for (; j < dg; ++j) a0 += h1pre[(size_t)esrc[base + j] * 128 + lane];
  float acc = ((a0 + a1) + (a2 + a3)) + ((a4 + a5) + (a6 + a7));
  const float inv = (dg > 0) ? 1.f / (float)dg : 0.f;
  h1[(size_t)d * 64 + lane] = acc * inv + b1[lane] + h1pre[(size_t)d * 128 + 64 + lane];
}

// ---------------- GEMM2: h1[50000,64] @ [W2_l|W2_r][64,64] -> m2[50000,64] ----------------
__global__ __launch_bounds__(256) void k_gemm2(const float* __restrict__ h1,
                                               const float* __restrict__ W2l,
                                               const float* __restrict__ W2r,
                                               float* __restrict__ m2) {
  __shared__ __align__(16) float Ws[64][68];
  __shared__ __align__(16) float Hs[32][68];
  const int t = threadIdx.x;
#pragma unroll
  for (int i = 0; i < 16; ++i) {
    int idx = t + 256 * i;
    int k = idx >> 6, c = idx & 63;
    Ws[k][c] = (c < 32) ? W2l[k * 32 + c] : W2r[k * 32 + (c - 32)];
  }
  const int r0 = blockIdx.x * 32;
#pragma unroll
  for (int i = 0; i < 8; ++i) {
    int idx = t + 256 * i;
    int r = idx >> 6, c = idx & 63;
    int gr = r0 + r;
    Hs[r][c] = (gr < N_NODES) ? h1[(size_t)gr * 64 + c] : 0.f;
  }
  __syncthreads();
  const int rl = t >> 3;
  const int c0 = (t & 7) * 8;
  float acc[8] = {};
#pragma unroll 8
  for (int k = 0; k < 64; ++k) {
    float hv = Hs[rl][k];
#pragma unroll
    for (int j = 0; j < 8; ++j) acc[j] = fmaf(hv, Ws[k][c0 + j], acc[j]);
  }
  const int gr = r0 + rl;
  if (gr < N_NODES) {
    *(float4*)(&m2[(size_t)gr * 64 + c0])     = make_float4(acc[0], acc[1], acc[2], acc[3]);
    *(float4*)(&m2[(size_t)gr * 64 + c0 + 4]) = make_float4(acc[4], acc[5], acc[6], acc[7]);
  }
}

// ---------------- aggregate layer 2 + relu + log_softmax, 8-way unrolled ----------------
__global__ __launch_bounds__(256) void k_agg2(const float* __restrict__ m2,
                                              const int* __restrict__ off,
                                              const int* __restrict__ deg,
                                              const int* __restrict__ esrc,
                                              const float* __restrict__ b2,
                                              float* __restrict__ out) {
  const int lane = threadIdx.x & 63;
  const int half = lane >> 5;
  const int f = lane & 31;
  const int d = blockIdx.x * 8 + ((threadIdx.x >> 6) << 1) + half;  // 50000 % 8 == 0
  const int dg = deg[d];
  const int base = off[d];
  float a0 = 0.f, a1 = 0.f, a2 = 0.f, a3 = 0.f;
  float a4 = 0.f, a5 = 0.f, a6 = 0.f, a7 = 0.f;
  int j = 0;
  for (; j + 8 <= dg; j += 8) {
    int s0 = esrc[base + j],     s1 = esrc[base + j + 1];
    int s2 = esrc[base + j + 2], s3 = esrc[base + j + 3];
    int s4 = esrc[base + j + 4], s5 = esrc[base + j + 5];
    int s6 = esrc[base + j + 6], s7 = esrc[base + j + 7];
    a0 += m2[(size_t)s0 * 64 + f];
    a1 += m2[(size_t)s1 * 64 + f];
    a2 += m2[(size_t)s2 * 64 + f];
    a3 += m2[(size_t)s3 * 64 + f];
    a4 += m2[(size_t)s4 * 64 + f];
    a5 += m2[(size_t)s5 * 64 + f];
    a6 += m2[(size_t)s6 * 64 + f];
    a7 += m2[(size_t)s7 * 64 + f];
  }
  for (; j + 4 <= dg; j += 4) {
    int s0 = esrc[base + j],     s1 = esrc[base + j + 1];
    int s2 = esrc[base + j + 2], s3 = esrc[base + j + 3];
    a0 += m2[(size_t)s0 * 64 + f];
    a1 += m2[(size_t)s1 * 64 + f];
    a2 += m2[(size_t)s2 * 64 + f];
    a3 += m2[(size_t)s3 * 64 + f];
  }
  for (; j < dg; ++j) a0 += m2[(size_t)esrc[base + j] * 64 + f];
  float acc = ((a0 + a1) + (a2 + a3)) + ((a4 + a5) + (a6 + a7));
  const float inv = (dg > 0) ? 1.f / (float)dg : 0.f;
  float v = acc * inv + b2[f] + m2[(size_t)d * 64 + 32 + f];
  v = fmaxf(v, 0.f);
  float m = v;
#pragma unroll
  for (int o = 16; o > 0; o >>= 1) m = fmaxf(m, __shfl_xor(m, o, 32));
  float e = expf(v - m);
  float sum = e;
#pragma unroll
  for (int o = 16; o > 0; o >>= 1) sum += __shfl_xor(sum, o, 32);
  out[(size_t)d * 32 + f] = v - m - logf(sum);
}

extern "C" void kernel_launch(void* const* d_in, const int* in_sizes, int n_in,
                              void* d_out, int out_size, void* d_ws, size_t ws_size,
                              hipStream_t stream) {
  const float* x   = (const float*)d_in[0];
  const int*   ei  = (const int*)d_in[1];
  const float* W1l = (const float*)d_in[2];
  const float* b1  = (const float*)d_in[3];
  const float* W1r = (const float*)d_in[4];
  const float* W2l = (const float*)d_in[5];
  const float* b2  = (const float*)d_in[6];
  const float* W2r = (const float*)d_in[7];
  float* out = (float*)d_out;

  char* ws = (char*)d_ws;
  float*  h1pre = (float*)(ws + OFF_H1PRE);
  float*  h1    = (float*)(ws + OFF_H1);
  float*  m2    = (float*)(ws + OFF_M2);
  int*    deg   = (int*)(ws + OFF_DEG);
  int*    off   = (int*)(ws + OFF_OFFS);
  int*    cur   = (int*)(ws + OFF_CUR);
  int*    esrc  = (int*)(ws + OFF_ESRC);
  int*    bsum  = (int*)(ws + OFF_BSUM);
  ushort* Wt    = (ushort*)(ws + OFF_WT);

  k_zero_deg<<<(N_NODES + 255) / 256, 256, 0, stream>>>(deg);

  {
    dim3 g(128, (KP + 255) / 256);
    k_prep_w<<<g, 256, 0, stream>>>(W1l, W1r, Wt);
  }
  k_gemm1f<<<(N_NODES + 31) / 32, 256, 0, stream>>>(x, Wt, h1pre);

  k_hist<<<(N_EDGES + 255) / 256, 256, 0, stream>>>(ei, deg);
  k_scan_a<<<25, 256, 0, stream>>>(deg, off, bsum);
  k_scan_c<<<(N_NODES + 255) / 256, 256, 0, stream>>>(off, cur, bsum);
  k_fill<<<(N_EDGES + 255) / 256, 256, 0, stream>>>(ei, cur, esrc);

  k_agg1<<<N_NODES / 4, 256, 0, stream>>>(h1pre, off, deg, esrc, b1, h1);
  k_gemm2<<<(N_NODES + 31) / 32, 256, 0, stream>>>(h1, W2l, W2r, m2);
  k_agg2<<<N_NODES / 8, 256, 0, stream>>>(m2, off, deg, esrc, b2, out);
}